// Round 6
// baseline (711.941 us; speedup 1.0000x reference)
//
#include <hip/hip_runtime.h>
#include <hip/hip_bf16.h>
#include <stdint.h>

#define N_NODES 50000
#define N_EDGES 800000
#define D_IN    788
#define D_INP   800   // K padded to 25*32
#define D_HID   256
#define N_REL   7
#define NBINS   (N_REL * N_NODES)   // 350000
#define NSCANB  342                 // ceil(350000/1024)
#define NXTILE  391                 // ceil(50000/128)

typedef __attribute__((ext_vector_type(8))) short bf16x8;
typedef __attribute__((ext_vector_type(4))) float f32x4;
typedef __attribute__((ext_vector_type(4))) unsigned int u32x4;

// RNE float->bf16 via compiler cast (emits v_cvt_pk_bf16_f32 when pairable)
__device__ __forceinline__ unsigned short f2bf(float f) {
  union { __hip_bfloat16 h; unsigned short u; } v;
  v.h = __float2bfloat16(f);
  return v.u;
}

__device__ __forceinline__ f32x4 bf4(ushort4 g) {
  union { unsigned int u; float f; } a, b, c, d;
  a.u = (unsigned)g.x << 16; b.u = (unsigned)g.y << 16;
  c.u = (unsigned)g.z << 16; d.u = (unsigned)g.w << 16;
  return (f32x4){a.f, b.f, c.f, d.f};
}

// async global->LDS, 16B per lane (wave-uniform LDS base + lane*16)
#define GLOAD16(g, l) __builtin_amdgcn_global_load_lds(                      \
    (const __attribute__((address_space(1))) unsigned int*)(g),              \
    (__attribute__((address_space(3))) unsigned int*)(l), 16, 0, 0)

// ---- weights -> bf16, [mat][o][k] with granule swizzle baked in ----
// v2 (coalesced): one thread per (mat, o, chunk). Lane index = o makes the
// src[(k)*D_HID + o] reads fully coalesced (1KB/wave/load); old per-lane-k
// layout fetched a distinct 64B line per 4B scalar (~105MB for 6.4MB data).
// Within each 32-elem K-chunk (4 granules of 8), content granule g is stored
// at position p = g ^ ((o>>1)&3); reader unswizzles with the same XOR.
__global__ void k_conv_w(const float* __restrict__ w_rel, const float* __restrict__ w_root,
                         unsigned short* __restrict__ wt) {
  int b = blockIdx.x;                 // grid = 8 mats * 25 chunks
  int m = b / 25, chunk = b % 25;
  int o = threadIdx.x;                // 256 threads = one per output col
  const float* src = (m < N_REL) ? (w_rel + (size_t)m * D_IN * D_HID) : w_root;
  int k0 = chunk * 32;

  unsigned short v[32];
#pragma unroll
  for (int kk = 0; kk < 32; kk++) {
    int k = k0 + kk;
    v[kk] = (k < D_IN) ? f2bf(src[(size_t)k * D_HID + o]) : (unsigned short)0;
  }

  unsigned short* dst = wt + ((size_t)m * D_HID + o) * D_INP + chunk * 32;
  int sw = (o >> 1) & 3;
#pragma unroll
  for (int g = 0; g < 4; g++) {
    union { unsigned short us[8]; u32x4 u; } pk;
#pragma unroll
    for (int j = 0; j < 8; j++) pk.us[j] = v[g * 8 + j];
    *(u32x4*)(dst + (g ^ sw) * 8) = pk.u;    // 4x16B fill the 64B chunk
  }
}

// ---- x -> bf16, padded to D_INP, same granule swizzle, pad zeroed ----
__global__ void k_xbf(const float* __restrict__ x, unsigned short* __restrict__ xb) {
  int t = blockIdx.x * blockDim.x + threadIdx.x;   // one thread per 8-elem granule
  if (t >= N_NODES * 100) return;
  int n = t / 100, gi = t % 100;
  int chunk = gi >> 2, p = gi & 3;
  int g = p ^ ((n >> 1) & 3);
  int c = chunk * 32 + g * 8;
  union { unsigned short us[8]; u32x4 v; } pk;
  if (c + 7 < D_IN) {
    float4 a = *(const float4*)(x + (size_t)n * D_IN + c);
    float4 b = *(const float4*)(x + (size_t)n * D_IN + c + 4);
    pk.us[0] = f2bf(a.x); pk.us[1] = f2bf(a.y); pk.us[2] = f2bf(a.z); pk.us[3] = f2bf(a.w);
    pk.us[4] = f2bf(b.x); pk.us[5] = f2bf(b.y); pk.us[6] = f2bf(b.z); pk.us[7] = f2bf(b.w);
  } else {
#pragma unroll
    for (int j = 0; j < 8; j++)
      pk.us[j] = (c + j < D_IN) ? f2bf(x[(size_t)n * D_IN + c + j]) : (unsigned short)0;
  }
  *(u32x4*)(xb + (size_t)n * D_INP + chunk * 32 + p * 8) = pk.v;
}

// ---- per-(rel,dst) edge counts ----
__global__ void k_count(const int* __restrict__ etype, const int* __restrict__ edst,
                        int* __restrict__ cnt) {
  int t = blockIdx.x * blockDim.x + threadIdx.x;
  if (t >= N_EDGES) return;
  atomicAdd(&cnt[etype[t] * N_NODES + edst[t]], 1);
}

// ==== exclusive scan of cnt[350000] -> S (3 kernels) ====
__global__ void k_scan1(const int* __restrict__ cnt, int* __restrict__ bsum) {
  __shared__ int wsh[4];
  int b = blockIdx.x, tid = threadIdx.x;
  int base = b * 1024 + tid * 4;
  int4 v = {0, 0, 0, 0};
  if (base + 3 < NBINS) v = *(const int4*)(cnt + base);
  else { for (int i = 0; i < 4; i++) if (base + i < NBINS) ((int*)&v)[i] = cnt[base + i]; }
  int s = v.x + v.y + v.z + v.w;
  for (int o = 32; o > 0; o >>= 1) s += __shfl_down(s, o);
  if ((tid & 63) == 0) wsh[tid >> 6] = s;
  __syncthreads();
  if (tid == 0) bsum[b] = wsh[0] + wsh[1] + wsh[2] + wsh[3];
}

__global__ void k_scan2(const int* __restrict__ bsum, int* __restrict__ boff) {
  __shared__ int tmp[512];
  int tid = threadIdx.x;
  int mine = (tid < NSCANB) ? bsum[tid] : 0;
  tmp[tid] = mine;
  __syncthreads();
  for (int o = 1; o < 512; o <<= 1) {
    int v = (tid >= o) ? tmp[tid - o] : 0;
    __syncthreads();
    tmp[tid] += v;
    __syncthreads();
  }
  if (tid < NSCANB) boff[tid] = tmp[tid] - mine;   // exclusive
}

__global__ void k_scan3(const int* __restrict__ cnt, const int* __restrict__ boff,
                        int* __restrict__ S) {
  __shared__ int wsum[4];
  int b = blockIdx.x, tid = threadIdx.x;
  int base = b * 1024 + tid * 4;
  int4 v = {0, 0, 0, 0};
  if (base + 3 < NBINS) v = *(const int4*)(cnt + base);
  else { for (int i = 0; i < 4; i++) if (base + i < NBINS) ((int*)&v)[i] = cnt[base + i]; }
  int s = v.x + v.y + v.z + v.w;
  int lane = tid & 63, w = tid >> 6;
  int sc = s;
  for (int o = 1; o < 64; o <<= 1) { int u = __shfl_up(sc, o); if (lane >= o) sc += u; }
  if (lane == 63) wsum[w] = sc;
  __syncthreads();
  int wbase = 0;
  for (int i = 0; i < w; i++) wbase += wsum[i];
  int excl = boff[b] + wbase + sc - s;
  int o0 = excl, o1 = excl + v.x, o2 = o1 + v.y, o3 = o2 + v.z;
  if (base + 3 < NBINS) { int4 o4 = {o0, o1, o2, o3}; *(int4*)(S + base) = o4; }
  else {
    if (base     < NBINS) S[base]     = o0;
    if (base + 1 < NBINS) S[base + 1] = o1;
    if (base + 2 < NBINS) S[base + 2] = o2;
    if (base + 3 < NBINS) S[base + 3] = o3;
  }
}

// ---- scatter edge SOURCES into bin-sorted order ----
__global__ void k_scatter(const int* __restrict__ etype, const int* __restrict__ edst,
                          const int* __restrict__ esrc, const int* __restrict__ S,
                          int* __restrict__ rank, int* __restrict__ psrc) {
  int t = blockIdx.x * blockDim.x + threadIdx.x;
  if (t >= N_EDGES) return;
  int bin = etype[t] * N_NODES + edst[t];
  int r = atomicAdd(&rank[bin], 1);
  psrc[S[bin] + r] = esrc[t];
}

// ---- bf16 GEMM: 128x256 tile, 8 waves (2M x 4N, each 64x64), BK=32,
// DOUBLE-buffered LDS 2-phase (T3-minimum): per K-step issue next-tile
// global_load_lds into buf^1 FIRST, then ds_read+MFMA current buf, then
// __syncthreads (its vmcnt(0) drain lands AFTER compute -> loads overlap).
// Linear LDS dest (pre-swizzled sources); reads unswizzle granule =
// quad ^ ((row>>1)&3). SWZ=1: XCD-chunked bijection, A-tile L2 reuse.
template<int SWZ, int NMAT>
__global__ __launch_bounds__(512) void k_gemm_g(
    const unsigned short* __restrict__ xb, const unsigned short* __restrict__ wt,
    unsigned short* __restrict__ xrs, int mb) {
  __shared__ __align__(16) unsigned short As[2][128 * 32];   // 2 x 8 KB
  __shared__ __align__(16) unsigned short Bs[2][256 * 32];   // 2 x 16 KB

  int tid = threadIdx.x;
  int bx, by;
  if (SWZ) {
    int b = blockIdx.x;                       // grid = NXTILE * NMAT (1D)
    int l = (b % 8) * (NXTILE * NMAT / 8) + b / 8;   // XCD-chunked (grid % 8 == 0)
    bx = l / NMAT; by = l % NMAT;             // consecutive l share bx -> A reuse
  } else {
    bx = blockIdx.x; by = blockIdx.y;
  }
  int mat = mb + by;
  int m0 = bx * 128;
  const unsigned short* wsec = wt + (size_t)mat * (D_HID * D_INP);
  int lane = tid & 63, w = tid >> 6;
  int wm = w >> 2, wn = w & 3;

  // staging sources (linear copy of pre-swizzled data)
  int ar = tid >> 2;                                   // A row 0..127
  int arow = m0 + ar; if (arow > N_NODES - 1) arow = N_NODES - 1;
  const unsigned short* asrc = xb + (size_t)arow * D_INP + (tid & 3) * 8;
  const unsigned short* bsrc0 = wsec + (size_t)(tid >> 2) * D_INP + (tid & 3) * 8;
  const unsigned short* bsrc1 = bsrc0 + (size_t)128 * D_INP;

  f32x4 acc[4][4];
#pragma unroll
  for (int i = 0; i < 4; i++)
#pragma unroll
    for (int j = 0; j < 4; j++) acc[i][j] = (f32x4){0.f, 0.f, 0.f, 0.f};

  int row = lane & 15, quad = lane >> 4;
  int rg = (quad ^ ((row >> 1) & 3)) * 8;              // unswizzled granule offset

  // prologue: stage ks=0 into buf0; barrier drains vmcnt(0)
  GLOAD16(asrc,  &As[0][0] + tid * 8);
  GLOAD16(bsrc0, &Bs[0][0] + tid * 8);
  GLOAD16(bsrc1, &Bs[0][0] + 4096 + tid * 8);
  __syncthreads();

  int cur = 0;
  for (int ks = 0; ks < 25; ks++) {
    if (ks < 24) {                                     // issue next-tile loads first
      int ko = (ks + 1) * 32;
      GLOAD16(asrc + ko,  &As[cur ^ 1][0] + tid * 8);
      GLOAD16(bsrc0 + ko, &Bs[cur ^ 1][0] + tid * 8);
      GLOAD16(bsrc1 + ko, &Bs[cur ^ 1][0] + 4096 + tid * 8);
    }

    const unsigned short* Ac = &As[cur][0];
    const unsigned short* Bc = &Bs[cur][0];
    bf16x8 af[4], bfr[4];
#pragma unroll
    for (int i = 0; i < 4; i++)
      af[i] = *(const bf16x8*)(Ac + (wm * 64 + i * 16 + row) * 32 + rg);
#pragma unroll
    for (int j = 0; j < 4; j++)
      bfr[j] = *(const bf16x8*)(Bc + (wn * 64 + j * 16 + row) * 32 + rg);
#pragma unroll
    for (int i = 0; i < 4; i++)
#pragma unroll
      for (int j = 0; j < 4; j++)
        acc[i][j] = __builtin_amdgcn_mfma_f32_16x16x32_bf16(af[i], bfr[j], acc[i][j], 0, 0, 0);

    __syncthreads();   // vmcnt(0) drain AFTER compute: next loads overlapped
    cur ^= 1;
  }

  // epilogue: C layout col=lane&15, row=(lane>>4)*4+reg
  int col_l = lane & 15, rquad = lane >> 4;
  unsigned short* xo = xrs + (size_t)by * ((size_t)N_NODES * D_HID);
#pragma unroll
  for (int i = 0; i < 4; i++) {
#pragma unroll
    for (int reg = 0; reg < 4; reg++) {
      int node = m0 + wm * 64 + i * 16 + rquad * 4 + reg;
      if (node < N_NODES) {
#pragma unroll
        for (int j = 0; j < 4; j++)
          xo[(size_t)node * D_HID + wn * 64 + j * 16 + col_l] = f2bf(acc[i][j][reg]);
      }
    }
  }
}

// ---- fallback GEMM (small ws): reg-staged, fp32 x with convert. B-source
// granule adjusted to unswizzle the wt layout on load.
__global__ __launch_bounds__(256) void k_gemm_f(
    const float* __restrict__ x, const unsigned short* __restrict__ wt,
    unsigned short* __restrict__ xrs, int mb) {
  __shared__ __align__(16) unsigned short As[64 * 40];
  __shared__ __align__(16) unsigned short Bs[256 * 40];

  int tid = threadIdx.x;
  int mat = mb + blockIdx.y;
  int m0 = blockIdx.x * 64;
  const unsigned short* wsec = wt + (size_t)mat * (D_HID * D_INP);
  int lane = tid & 63, w = tid >> 6;

  int ra = tid >> 2, ca = tid & 3, ca8 = ca * 8;
  int arow = m0 + ra; if (arow > N_NODES - 1) arow = N_NODES - 1;
  const float* apf = x + (size_t)arow * D_IN;
  const unsigned short* bgp = wsec + (size_t)ra * D_INP + (ca ^ ((ra >> 1) & 3)) * 8;
  unsigned short* al = As + ra * 40 + ca8;
  unsigned short* bl = Bs + ra * 40 + ca8;

  f32x4 acc[4][4];
#pragma unroll
  for (int i = 0; i < 4; i++)
#pragma unroll
    for (int j = 0; j < 4; j++) acc[i][j] = (f32x4){0.f, 0.f, 0.f, 0.f};

  float4 pa0 = *(const float4*)(apf + ca8);
  float4 pa1 = *(const float4*)(apf + ca8 + 4);
  u32x4 pb0 = *(const u32x4*)(bgp);
  u32x4 pb1 = *(const u32x4*)(bgp +  64 * D_INP);
  u32x4 pb2 = *(const u32x4*)(bgp + 128 * D_INP);
  u32x4 pb3 = *(const u32x4*)(bgp + 192 * D_INP);

  int row = lane & 15, quad = lane >> 4;
  for (int ks = 0; ks < 25; ks++) {
    if (ks < 24) {
      union { unsigned short us[8]; u32x4 v; } pk;
      pk.us[0] = f2bf(pa0.x); pk.us[1] = f2bf(pa0.y);
      pk.us[2] = f2bf(pa0.z); pk.us[3] = f2bf(pa0.w);
      pk.us[4] = f2bf(pa1.x); pk.us[5] = f2bf(pa1.y);
      pk.us[6] = f2bf(pa1.z); pk.us[7] = f2bf(pa1.w);
      *(u32x4*)al = pk.v;
    } else {
      float v0 = pa0.x, v1 = pa0.y, v2 = pa0.z, v3 = pa0.w;
      float v4 = pa1.x, v5 = pa1.y, v6 = pa1.z, v7 = pa1.w;
      if (ca8 == 16) { v0 = pa1.x; v1 = pa1.y; v2 = pa1.z; v3 = pa1.w;
                       v4 = 0.f; v5 = 0.f; v6 = 0.f; v7 = 0.f; }
      if (ca8 == 24) { v0 = 0.f; v1 = 0.f; v2 = 0.f; v3 = 0.f;
                       v4 = 0.f; v5 = 0.f; v6 = 0.f; v7 = 0.f; }
      union { unsigned short us[8]; u32x4 v; } pk;
      pk.us[0] = f2bf(v0); pk.us[1] = f2bf(v1); pk.us[2] = f2bf(v2); pk.us[3] = f2bf(v3);
      pk.us[4] = f2bf(v4); pk.us[5] = f2bf(v5); pk.us[6] = f2bf(v6); pk.us[7] = f2bf(v7);
      *(u32x4*)al = pk.v;
    }
    *(u32x4*)bl = pb0;
    *(u32x4*)(bl +  64 * 40) = pb1;
    *(u32x4*)(bl + 128 * 40) = pb2;
    *(u32x4*)(bl + 192 * 40) = pb3;
    __syncthreads();

    if (ks < 24) {
      int on = (ks + 1) * 32 + ca8;
      int lo = (on > 780) ? 780 : on;
      pa0 = *(const float4*)(apf + lo);
      pa1 = *(const float4*)(apf + lo + 4);
      int ko = (ks + 1) * 32;
      pb0 = *(const u32x4*)(bgp + ko);
      pb1 = *(const u32x4*)(bgp + ko +  64 * D_INP);
      pb2 = *(const u32x4*)(bgp + ko + 128 * D_INP);
      pb3 = *(const u32x4*)(bgp + ko + 192 * D_INP);
    }

    bf16x8 af[4], bfr[4];
#pragma unroll
    for (int i = 0; i < 4; i++)
      af[i] = *(const bf16x8*)(As + (i * 16 + row) * 40 + quad * 8);
#pragma unroll
    for (int j = 0; j < 4; j++)
      bfr[j] = *(const bf16x8*)(Bs + (w * 64 + j * 16 + row) * 40 + quad * 8);
#pragma unroll
    for (int i = 0; i < 4; i++)
#pragma unroll
      for (int j = 0; j < 4; j++)
        acc[i][j] = __builtin_amdgcn_mfma_f32_16x16x32_bf16(af[i], bfr[j], acc[i][j], 0, 0, 0);
    __syncthreads();
  }

  int col_l = lane & 15, rquad = lane >> 4;
  unsigned short* xo = xrs + (size_t)blockIdx.y * ((size_t)N_NODES * D_HID);
#pragma unroll
  for (int i = 0; i < 4; i++) {
#pragma unroll
    for (int reg = 0; reg < 4; reg++) {
      int node = m0 + i * 16 + rquad * 4 + reg;
      if (node < N_NODES) {
#pragma unroll
        for (int j = 0; j < 4; j++)
          xo[(size_t)node * D_HID + w * 64 + j * 16 + col_l] = f2bf(acc[i][j][reg]);
      }
    }
  }
}

// ---- FULL-path aggregation: all 7 rels + root + bias + relu + fused layer-2
// in ONE pass (no h intermediate). One wave per node; xrs has 8 slabs.
// Epilogue v3: hv -> wave-local LDS, 8 lane-groups of 8 compute the 8 mats in
// parallel. Lane sl owns dims {sl*4 + j*32}: per-j the 8 lanes span 128B =
// all 32 banks (conflict-free); groups read identical addrs = broadcast.
__global__ __launch_bounds__(256) void k_agg8(
    const unsigned short* __restrict__ xrs, const int* __restrict__ S,
    const int* __restrict__ cnt, const int* __restrict__ psrc,
    const float* __restrict__ b1, const float* __restrict__ w2rel,
    const float* __restrict__ w2root, float* __restrict__ y) {
  __shared__ float hsh[4][256];                 // 4 KB, one row per wave
  int wv = threadIdx.x >> 6;
  int n = blockIdx.x * 4 + wv;                  // grid exactly covers 50000
  int lane = threadIdx.x & 63;
  if (n >= N_NODES) return;

  // lanes 0..6 prefetch cnt/S for all rels; broadcast via shfl
  int c_l = 0, p_l = 0;
  if (lane < N_REL) {
    c_l = cnt[lane * N_NODES + n];
    p_l = S[lane * N_NODES + n];
  }

  f32x4 acc = (f32x4){0.f, 0.f, 0.f, 0.f};
#pragma unroll
  for (int r = 0; r < N_REL; r++) {
    int c = __shfl(c_l, r);
    if (c > 0) {
      int p = __shfl(p_l, r);
      const unsigned short* slab = xrs + (size_t)r * N_NODES * D_HID;
      f32x4 s = (f32x4){0.f, 0.f, 0.f, 0.f};
      int e = 0;
      for (; e + 1 < c; e += 2) {
        int s0 = psrc[p + e], s1 = psrc[p + e + 1];
        ushort4 g0 = *(const ushort4*)(slab + (size_t)s0 * D_HID + lane * 4);
        ushort4 g1 = *(const ushort4*)(slab + (size_t)s1 * D_HID + lane * 4);
        s += bf4(g0) + bf4(g1);
      }
      if (e < c) {
        int s0 = psrc[p + e];
        ushort4 g0 = *(const ushort4*)(slab + (size_t)s0 * D_HID + lane * 4);
        s += bf4(g0);
      }
      acc += s * (1.0f / (float)c);
    }
  }

  // root (slab 7) + bias + relu
  ushort4 gr = *(const ushort4*)(xrs + ((size_t)7 * N_NODES + n) * D_HID + lane * 4);
  acc += bf4(gr);
  f32x4 b = *(const f32x4*)(b1 + lane * 4);
  f32x4 hv;
  hv[0] = fmaxf(acc[0] + b[0], 0.f);
  hv[1] = fmaxf(acc[1] + b[1], 0.f);
  hv[2] = fmaxf(acc[2] + b[2], 0.f);
  hv[3] = fmaxf(acc[3] + b[3], 0.f);

  // wave-local LDS stash (same-wave DS ops are in-order; fence the compiler)
  *(f32x4*)&hsh[wv][lane * 4] = hv;
  __builtin_amdgcn_wave_barrier();

  // 8 lane-groups x 8 lanes: group m computes y[m][n][0..1]
  int m = lane >> 3, sl = lane & 7;
  const float* wp = (m < N_REL) ? (w2rel + m * (D_HID * 2)) : w2root;
  float d0 = 0.f, d1 = 0.f;
#pragma unroll
  for (int j = 0; j < 8; j++) {
    int db = sl * 4 + j * 32;                  // conflict-free partition
    f32x4 h4 = *(const f32x4*)&hsh[wv][db];
    f32x4 wa = *(const f32x4*)(wp + db * 2);
    f32x4 wb = *(const f32x4*)(wp + db * 2 + 4);
    d0 += h4[0] * wa[0] + h4[1] * wa[2] + h4[2] * wb[0] + h4[3] * wb[2];
    d1 += h4[0] * wa[1] + h4[1] * wa[3] + h4[2] * wb[1] + h4[3] * wb[3];
  }
  d0 += __shfl_down(d0, 1); d1 += __shfl_down(d1, 1);
  d0 += __shfl_down(d0, 2); d1 += __shfl_down(d1, 2);
  d0 += __shfl_down(d0, 4); d1 += __shfl_down(d1, 4);
  if (sl == 0) {
    y[(size_t)m * (N_NODES * 2) + n * 2]     = d0;
    y[(size_t)m * (N_NODES * 2) + n * 2 + 1] = d1;
  }
}

// ---- fallback aggregation (4-pass, h intermediate) ----
__global__ __launch_bounds__(256) void k_agg(
    const unsigned short* __restrict__ xrs, const int* __restrict__ S,
    const int* __restrict__ cnt, const int* __restrict__ psrc,
    float* __restrict__ h, const float* __restrict__ b1,
    const float* __restrict__ w2rel, const float* __restrict__ w2root,
    float* __restrict__ y, int r0, int pass) {
  int n = blockIdx.x * 4 + (threadIdx.x >> 6);
  int lane = threadIdx.x & 63;
  if (n >= N_NODES) return;
  f32x4 acc;
  if (pass == 0) acc = (f32x4){0.f, 0.f, 0.f, 0.f};
  else acc = *(const f32x4*)(h + (size_t)n * D_HID + lane * 4);

  int nr = (pass < 3) ? 2 : 1;
  for (int rr = 0; rr < nr; rr++) {
    int bin = (r0 + rr) * N_NODES + n;
    int c = cnt[bin];
    if (c > 0) {
      int p = S[bin];
      f32x4 s = (f32x4){0.f, 0.f, 0.f, 0.f};
      int e = 0;
      for (; e + 1 < c; e += 2) {
        int s0 = psrc[p + e], s1 = psrc[p + e + 1];
        ushort4 g0 = *(const ushort4*)(xrs + ((size_t)rr * N_NODES + s0) * D_HID + lane * 4);
        ushort4 g1 = *(const ushort4*)(xrs + ((size_t)rr * N_NODES + s1) * D_HID + lane * 4);
        s += bf4(g0) + bf4(g1);
      }
      if (e < c) {
        int s0 = psrc[p + e];
        ushort4 g0 = *(const ushort4*)(xrs + ((size_t)rr * N_NODES + s0) * D_HID + lane * 4);
        s += bf4(g0);
      }
      acc += s * (1.0f / (float)c);
    }
  }

  if (pass < 3) {
    *(f32x4*)(h + (size_t)n * D_HID + lane * 4) = acc;
    return;
  }

  ushort4 gr = *(const ushort4*)(xrs + ((size_t)1 * N_NODES + n) * D_HID + lane * 4);
  acc += bf4(gr);
  f32x4 b = *(const f32x4*)(b1 + lane * 4);
  f32x4 hv;
  hv[0] = fmaxf(acc[0] + b[0], 0.f);
  hv[1] = fmaxf(acc[1] + b[1], 0.f);
  hv[2] = fmaxf(acc[2] + b[2], 0.f);
  hv[3] = fmaxf(acc[3] + b[3], 0.f);

#pragma unroll
  for (int m = 0; m < 8; m++) {
    const float* wp = (m < N_REL) ? (w2rel + m * (D_HID * 2)) : w2root;
    f32x4 wa = *(const f32x4*)(wp + lane * 8);
    f32x4 wb = *(const f32x4*)(wp + lane * 8 + 4);
    float d0 = hv[0] * wa[0] + hv[1] * wa[2] + hv[2] * wb[0] + hv[3] * wb[2];
    float d1 = hv[0] * wa[1] + hv[1] * wa[3] + hv[2] * wb[1] + hv[3] * wb[3];
#pragma unroll
    for (int off = 32; off > 0; off >>= 1) {
      d0 += __shfl_down(d0, off);
      d1 += __shfl_down(d1, off);
    }
    if (lane == 0) {
      y[(size_t)m * (N_NODES * 2) + n * 2]     = d0;
      y[(size_t)m * (N_NODES * 2) + n * 2 + 1] = d1;
    }
  }
}

// ---- layer-2 aggregation: thread per bin (mean over bin) + root/bias threads ----
__global__ void k_out(const float* __restrict__ y, const float* __restrict__ b2,
                      const int* __restrict__ cnt, const int* __restrict__ S,
                      const int* __restrict__ psrc, float* __restrict__ out) {
  int t = blockIdx.x * blockDim.x + threadIdx.x;
  if (t < NBINS) {
    int c = cnt[t];
    if (c == 0) return;
    int p = S[t];
    int r = t / N_NODES;
    int i = t - r * N_NODES;
    const float* yr = y + (size_t)r * (N_NODES * 2);
    float s0 = 0.f, s1 = 0.f;
    for (int e = 0; e < c; e++) {
      int sc = psrc[p + e];
      float2 v = *(const float2*)(yr + sc * 2);
      s0 += v.x; s1 += v.y;
    }
    float is = 1.0f / (float)c;
    atomicAdd(out + (size_t)i * 2,     s0 * is);
    atomicAdd(out + (size_t)i * 2 + 1, s1 * is);
  } else if (t < NBINS + N_NODES) {
    int i = t - NBINS;
    float2 v = *(const float2*)(y + (size_t)N_REL * (N_NODES * 2) + i * 2);
    atomicAdd(out + (size_t)i * 2,     v.x + b2[0]);
    atomicAdd(out + (size_t)i * 2 + 1, v.y + b2[1]);
  }
}

// ---- fallback (round-2) workspace layout; total 196,280,896 w/ xb ----
#define OFF_WT   0u
#define OFF_XRS  3276800u
#define OFF_H    54476800u
#define OFF_CNT  105676800u
#define OFF_RANK 107076800u
#define OFF_S    108476800u
#define OFF_PSRC 109876800u
#define OFF_Y    113076800u
#define OFF_BSUM 116276800u
#define OFF_BOFF 116278848u
#define OFF_XB   116280896u
#define WS_NEED_XB 196280896ull

// ---- FULL layout: 8-slab xrs, no h; total 298,680,896 ----
#define F_OFF_WT   0u            // 3,276,800
#define F_OFF_XRS  3276800u      // 8*50000*256*2 = 204,800,000
#define F_OFF_CNT  208076800u    // 1,400,000
#define F_OFF_RANK 209476800u    // 1,400,000
#define F_OFF_S    210876800u    // 1,400,000
#define F_OFF_PSRC 212276800u    // 3,200,000
#define F_OFF_Y    215476800u    // 3,200,000
#define F_OFF_BSUM 218676800u    // 2048
#define F_OFF_BOFF 218678848u    // 2048
#define F_OFF_XB   218680896u    // 80,000,000
#define WS_NEED_FULL 298680896ull

extern "C" void kernel_launch(void* const* d_in, const int* in_sizes, int n_in,
                              void* d_out, int out_size, void* d_ws, size_t ws_size,
                              hipStream_t stream) {
  const float* x      = (const float*)d_in[0];
  const int*   eidx   = (const int*)d_in[1];
  const int*   etype  = (const int*)d_in[2];
  const float* w1rel  = (const float*)d_in[3];
  const float* w1root = (const float*)d_in[4];
  const float* b1     = (const float*)d_in[5];
  const float* w2rel  = (const float*)d_in[6];
  const float* w2root = (const float*)d_in[7];
  const float* b2     = (const float*)d_in[8];
  float* out = (float*)d_out;
  char* ws = (char*)d_ws;
  const int* esrc = eidx;
  const int* edst = eidx + N_EDGES;

  const bool full = (ws_size >= WS_NEED_FULL);
  const bool big  = !full && (ws_size >= WS_NEED_XB);

  hipMemsetAsync(d_out, 0, (size_t)out_size * sizeof(float), stream);

  if (full) {
    unsigned short* wt  = (unsigned short*)(ws + F_OFF_WT);
    unsigned short* xrs = (unsigned short*)(ws + F_OFF_XRS);
    int*   cnt  = (int*)(ws + F_OFF_CNT);
    int*   rank = (int*)(ws + F_OFF_RANK);
    int*   S    = (int*)(ws + F_OFF_S);
    int*   psrc = (int*)(ws + F_OFF_PSRC);
    float* y    = (float*)(ws + F_OFF_Y);
    int*   bsum = (int*)(ws + F_OFF_BSUM);
    int*   boff = (int*)(ws + F_OFF_BOFF);
    unsigned short* xb = (unsigned short*)(ws + F_OFF_XB);

    hipMemsetAsync(ws + F_OFF_CNT, 0, 2800000u, stream);       // cnt + rank

    k_conv_w<<<8 * 25, 256, 0, stream>>>(w1rel, w1root, wt);
    k_xbf<<<(N_NODES * 100 + 255) / 256, 256, 0, stream>>>(x, xb);
    k_count<<<(N_EDGES + 255) / 256, 256, 0, stream>>>(etype, edst, cnt);
    k_scan1<<<NSCANB, 256, 0, stream>>>(cnt, bsum);
    k_scan2<<<1, 512, 0, stream>>>(bsum, boff);
    k_scan3<<<NSCANB, 256, 0, stream>>>(cnt, boff, S);
    k_scatter<<<(N_EDGES + 255) / 256, 256, 0, stream>>>(etype, edst, esrc, S, rank, psrc);

    k_gemm_g<1, 8><<<NXTILE * 8, 512, 0, stream>>>(xb, wt, xrs, 0);
    k_agg8<<<(N_NODES + 3) / 4, 256, 0, stream>>>(xrs, S, cnt, psrc,
                                                  b1, w2rel, w2root, y);
    k_out<<<(NBINS + N_NODES + 255) / 256, 256, 0, stream>>>(y, b2, cnt, S, psrc, out);
    return;
  }

  unsigned short* wt  = (unsigned short*)(ws + OFF_WT);
  unsigned short* xrs = (unsigned short*)(ws + OFF_XRS);
  float* h    = (float*)(ws + OFF_H);
  int*   cnt  = (int*)(ws + OFF_CNT);
  int*   rank = (int*)(ws + OFF_RANK);
  int*   S    = (int*)(ws + OFF_S);
  int*   psrc = (int*)(ws + OFF_PSRC);
  float* y    = (float*)(ws + OFF_Y);
  int*   bsum = (int*)(ws + OFF_BSUM);
  int*   boff = (int*)(ws + OFF_BOFF);
  unsigned short* xb = (unsigned short*)(ws + OFF_XB);

  hipMemsetAsync(ws + OFF_CNT, 0, 2800000u, stream);           // cnt + rank

  k_conv_w<<<8 * 25, 256, 0, stream>>>(w1rel, w1root, wt);
  if (big)
    k_xbf<<<(N_NODES * 100 + 255) / 256, 256, 0, stream>>>(x, xb);
  k_count<<<(N_EDGES + 255) / 256, 256, 0, stream>>>(etype, edst, cnt);
  k_scan1<<<NSCANB, 256, 0, stream>>>(cnt, bsum);
  k_scan2<<<1, 512, 0, stream>>>(bsum, boff);
  k_scan3<<<NSCANB, 256, 0, stream>>>(cnt, boff, S);
  k_scatter<<<(N_EDGES + 255) / 256, 256, 0, stream>>>(etype, edst, esrc, S, rank, psrc);

  for (int p = 0; p < 4; p++) {
    if (big)
      k_gemm_g<0, 2><<<dim3(NXTILE, 2), 512, 0, stream>>>(xb, wt, xrs, 2 * p);
    else
      k_gemm_f<<<dim3(782, 2), 256, 0, stream>>>(x, wt, xrs, 2 * p);
    k_agg<<<(N_NODES + 3) / 4, 256, 0, stream>>>(xrs, S, cnt, psrc, h,
                                                 b1, w2rel, w2root, y, 2 * p, p);
  }

  k_out<<<(NBINS + N_NODES + 255) / 256, 256, 0, stream>>>(y, b2, cnt, S, psrc, out);
}

// Round 7
// 682.837 us; speedup vs baseline: 1.0426x; 1.0426x over previous
//
#include <hip/hip_runtime.h>
#include <hip/hip_bf16.h>
#include <stdint.h>

#define N_NODES 50000
#define N_EDGES 800000
#define D_IN    788
#define D_INP   832   // K padded to 13*64 (BK=64, no tail step)
#define D_HID   256
#define N_REL   7
#define NBINS   (N_REL * N_NODES)   // 350000
#define NSCANB  342                 // ceil(350000/1024)
#define NXTILE  391                 // ceil(50000/128)

typedef __attribute__((ext_vector_type(8))) short bf16x8;
typedef __attribute__((ext_vector_type(4))) float f32x4;
typedef __attribute__((ext_vector_type(4))) unsigned int u32x4;

// RNE float->bf16 via compiler cast (emits v_cvt_pk_bf16_f32 when pairable)
__device__ __forceinline__ unsigned short f2bf(float f) {
  union { __hip_bfloat16 h; unsigned short u; } v;
  v.h = __float2bfloat16(f);
  return v.u;
}

__device__ __forceinline__ f32x4 bf4(ushort4 g) {
  union { unsigned int u; float f; } a, b, c, d;
  a.u = (unsigned)g.x << 16; b.u = (unsigned)g.y << 16;
  c.u = (unsigned)g.z << 16; d.u = (unsigned)g.w << 16;
  return (f32x4){a.f, b.f, c.f, d.f};
}

// async global->LDS, 16B per lane (wave-uniform LDS base + lane*16)
#define GLOAD16(g, l) __builtin_amdgcn_global_load_lds(                      \
    (const __attribute__((address_space(1))) unsigned int*)(g),              \
    (__attribute__((address_space(3))) unsigned int*)(l), 16, 0, 0)

// ---- Swizzle convention (producers + readers, must match — rule #21) ----
// Row r (node for A, out-col o for B), 26 chunks of 32 elems, 4 granules of 8
// per chunk:
//   position chunk pc holds CONTENT chunk pc ^ (r&1)      (pairs swap in 64-group)
//   position granule p holds CONTENT granule p ^ ((r>>1)&3)
// BK=64 LDS rows are 128B; the parity-chunk-swap restores the odd-row +16-bank
// offset so ds_read_b128 fragments hit all 32 banks at 2 lanes/bank (free).

// ---- weights -> bf16, [mat][o][k] swizzled, coalesced reads ----
__global__ void k_conv_w(const float* __restrict__ w_rel, const float* __restrict__ w_root,
                         unsigned short* __restrict__ wt) {
  int b = blockIdx.x;                 // grid = 8 mats * 26 pos-chunks
  int m = b / 26, pc = b % 26;
  int o = threadIdx.x;                // 256 threads = one per output col
  const float* src = (m < N_REL) ? (w_rel + (size_t)m * D_IN * D_HID) : w_root;
  int cc = pc ^ (o & 1);              // content chunk stored at this position
  int k0 = cc * 32;

  unsigned short v[32];
#pragma unroll
  for (int kk = 0; kk < 32; kk++) {
    int k = k0 + kk;
    v[kk] = (k < D_IN) ? f2bf(src[(size_t)k * D_HID + o]) : (unsigned short)0;
  }

  unsigned short* dst = wt + ((size_t)m * D_HID + o) * D_INP + pc * 32;
  int sw = (o >> 1) & 3;
#pragma unroll
  for (int g = 0; g < 4; g++) {       // content granule g -> position g^sw
    union { unsigned short us[8]; u32x4 u; } pk;
#pragma unroll
    for (int j = 0; j < 8; j++) pk.us[j] = v[g * 8 + j];
    *(u32x4*)(dst + (g ^ sw) * 8) = pk.u;
  }
}

// ---- x -> bf16, padded to D_INP, same swizzle, pad zeroed ----
__global__ void k_xbf(const float* __restrict__ x, unsigned short* __restrict__ xb) {
  int t = blockIdx.x * blockDim.x + threadIdx.x;   // one thread per 8-elem granule
  if (t >= N_NODES * 104) return;
  int n = t / 104, gi = t % 104;
  int pc = gi >> 2, p = gi & 3;
  int cc = pc ^ (n & 1);
  int g = p ^ ((n >> 1) & 3);
  int c = cc * 32 + g * 8;            // content k0
  union { unsigned short us[8]; u32x4 v; } pk;
  if (c + 7 < D_IN) {
    float4 a = *(const float4*)(x + (size_t)n * D_IN + c);
    float4 b = *(const float4*)(x + (size_t)n * D_IN + c + 4);
    pk.us[0] = f2bf(a.x); pk.us[1] = f2bf(a.y); pk.us[2] = f2bf(a.z); pk.us[3] = f2bf(a.w);
    pk.us[4] = f2bf(b.x); pk.us[5] = f2bf(b.y); pk.us[6] = f2bf(b.z); pk.us[7] = f2bf(b.w);
  } else {
#pragma unroll
    for (int j = 0; j < 8; j++)
      pk.us[j] = (c + j < D_IN) ? f2bf(x[(size_t)n * D_IN + c + j]) : (unsigned short)0;
  }
  *(u32x4*)(xb + (size_t)n * D_INP + pc * 32 + p * 8) = pk.v;
}

// ---- per-(rel,dst) edge counts ----
__global__ void k_count(const int* __restrict__ etype, const int* __restrict__ edst,
                        int* __restrict__ cnt) {
  int t = blockIdx.x * blockDim.x + threadIdx.x;
  if (t >= N_EDGES) return;
  atomicAdd(&cnt[etype[t] * N_NODES + edst[t]], 1);
}

// ==== exclusive scan of cnt[350000] -> S (3 kernels) ====
__global__ void k_scan1(const int* __restrict__ cnt, int* __restrict__ bsum) {
  __shared__ int wsh[4];
  int b = blockIdx.x, tid = threadIdx.x;
  int base = b * 1024 + tid * 4;
  int4 v = {0, 0, 0, 0};
  if (base + 3 < NBINS) v = *(const int4*)(cnt + base);
  else { for (int i = 0; i < 4; i++) if (base + i < NBINS) ((int*)&v)[i] = cnt[base + i]; }
  int s = v.x + v.y + v.z + v.w;
  for (int o = 32; o > 0; o >>= 1) s += __shfl_down(s, o);
  if ((tid & 63) == 0) wsh[tid >> 6] = s;
  __syncthreads();
  if (tid == 0) bsum[b] = wsh[0] + wsh[1] + wsh[2] + wsh[3];
}

__global__ void k_scan2(const int* __restrict__ bsum, int* __restrict__ boff) {
  __shared__ int tmp[512];
  int tid = threadIdx.x;
  int mine = (tid < NSCANB) ? bsum[tid] : 0;
  tmp[tid] = mine;
  __syncthreads();
  for (int o = 1; o < 512; o <<= 1) {
    int v = (tid >= o) ? tmp[tid - o] : 0;
    __syncthreads();
    tmp[tid] += v;
    __syncthreads();
  }
  if (tid < NSCANB) boff[tid] = tmp[tid] - mine;   // exclusive
}

__global__ void k_scan3(const int* __restrict__ cnt, const int* __restrict__ boff,
                        int* __restrict__ S) {
  __shared__ int wsum[4];
  int b = blockIdx.x, tid = threadIdx.x;
  int base = b * 1024 + tid * 4;
  int4 v = {0, 0, 0, 0};
  if (base + 3 < NBINS) v = *(const int4*)(cnt + base);
  else { for (int i = 0; i < 4; i++) if (base + i < NBINS) ((int*)&v)[i] = cnt[base + i]; }
  int s = v.x + v.y + v.z + v.w;
  int lane = tid & 63, w = tid >> 6;
  int sc = s;
  for (int o = 1; o < 64; o <<= 1) { int u = __shfl_up(sc, o); if (lane >= o) sc += u; }
  if (lane == 63) wsum[w] = sc;
  __syncthreads();
  int wbase = 0;
  for (int i = 0; i < w; i++) wbase += wsum[i];
  int excl = boff[b] + wbase + sc - s;
  int o0 = excl, o1 = excl + v.x, o2 = o1 + v.y, o3 = o2 + v.z;
  if (base + 3 < NBINS) { int4 o4 = {o0, o1, o2, o3}; *(int4*)(S + base) = o4; }
  else {
    if (base     < NBINS) S[base]     = o0;
    if (base + 1 < NBINS) S[base + 1] = o1;
    if (base + 2 < NBINS) S[base + 2] = o2;
    if (base + 3 < NBINS) S[base + 3] = o3;
  }
}

// ---- scatter edge SOURCES into bin-sorted order ----
__global__ void k_scatter(const int* __restrict__ etype, const int* __restrict__ edst,
                          const int* __restrict__ esrc, const int* __restrict__ S,
                          int* __restrict__ rank, int* __restrict__ psrc) {
  int t = blockIdx.x * blockDim.x + threadIdx.x;
  if (t >= N_EDGES) return;
  int bin = etype[t] * N_NODES + edst[t];
  int r = atomicAdd(&rank[bin], 1);
  psrc[S[bin] + r] = esrc[t];
}

// ---- bf16 GEMM v3: 128x256 tile, 8 waves (2M x 4N, each 64x64), BK=64,
// 13 K-steps (vs 25 at BK=32): halves the per-step stage+vmcnt+barrier
// overhead that m233-style analysis shows dominates 2-phase schedules.
// Single-buffered 48 KB LDS (3 blocks/CU), global_load_lds width-16 staging
// (linear dest; sources pre-swizzled per the convention above).
// SWZ=1: XCD-chunked bijection so the NMAT col-blocks sharing an A-tile run
// consecutively on one XCD (A-tile L2 reuse).
template<int SWZ, int NMAT>
__global__ __launch_bounds__(512) void k_gemm_g(
    const unsigned short* __restrict__ xb, const unsigned short* __restrict__ wt,
    unsigned short* __restrict__ xrs, int mb) {
  __shared__ __align__(16) unsigned short As[128 * 64];   // 16 KB
  __shared__ __align__(16) unsigned short Bs[256 * 64];   // 32 KB

  int tid = threadIdx.x;
  int bx, by;
  if (SWZ) {
    int b = blockIdx.x;                       // grid = NXTILE * NMAT (1D), %8==0
    int l = (b % 8) * (NXTILE * NMAT / 8) + b / 8;
    bx = l / NMAT; by = l % NMAT;             // consecutive l share bx -> A reuse
  } else {
    bx = blockIdx.x; by = blockIdx.y;
  }
  int mat = mb + by;
  int m0 = bx * 128;
  const unsigned short* wsec = wt + (size_t)mat * (D_HID * D_INP);
  int lane = tid & 63, w = tid >> 6;
  int wm = w >> 2, wn = w & 3;

  // staging: thread covers 16B granule sg of rows sr / sr+64 (A) and the four
  // 64-row B groups. Linear LDS dest = linear copy of pre-swizzled global rows.
  int sr = tid >> 3, sg = (tid & 7) * 8;
  int ar0 = m0 + sr;      if (ar0 > N_NODES - 1) ar0 = N_NODES - 1;
  int ar1 = m0 + 64 + sr; if (ar1 > N_NODES - 1) ar1 = N_NODES - 1;
  const unsigned short* asrc0 = xb + (size_t)ar0 * D_INP + sg;
  const unsigned short* asrc1 = xb + (size_t)ar1 * D_INP + sg;
  const unsigned short* bsrc0 = wsec + (size_t)sr * D_INP + sg;
  const unsigned short* bsrc1 = bsrc0 + (size_t)64 * D_INP;
  const unsigned short* bsrc2 = bsrc0 + (size_t)128 * D_INP;
  const unsigned short* bsrc3 = bsrc0 + (size_t)192 * D_INP;
  unsigned short* al0 = As + tid * 8;
  unsigned short* al1 = As + 4096 + tid * 8;
  unsigned short* bl0 = Bs + tid * 8;
  unsigned short* bl1 = Bs + 4096 + tid * 8;
  unsigned short* bl2 = Bs + 8192 + tid * 8;
  unsigned short* bl3 = Bs + 12288 + tid * 8;

  f32x4 acc[4][4];
#pragma unroll
  for (int i = 0; i < 4; i++)
#pragma unroll
    for (int j = 0; j < 4; j++) acc[i][j] = (f32x4){0.f, 0.f, 0.f, 0.f};

  int row = lane & 15, quad = lane >> 4;
  int rg = (quad ^ ((row >> 1) & 3)) * 8;      // granule unswizzle
  int cp0 = (row & 1) * 32;                    // chunk pos for kk=0 (0^parity)
  int cp1 = 32 - cp0;                          // chunk pos for kk=1 (1^parity)

  for (int ks = 0; ks < 13; ks++) {
    int ko = ks * 64;
    GLOAD16(asrc0 + ko, al0);
    GLOAD16(asrc1 + ko, al1);
    GLOAD16(bsrc0 + ko, bl0);
    GLOAD16(bsrc1 + ko, bl1);
    GLOAD16(bsrc2 + ko, bl2);
    GLOAD16(bsrc3 + ko, bl3);
    __syncthreads();                           // drains vmcnt before barrier

    bf16x8 af[4], bfr[4];
    // kk = 0
#pragma unroll
    for (int i = 0; i < 4; i++)
      af[i] = *(const bf16x8*)(As + (wm * 64 + i * 16 + row) * 64 + cp0 + rg);
#pragma unroll
    for (int j = 0; j < 4; j++)
      bfr[j] = *(const bf16x8*)(Bs + (wn * 64 + j * 16 + row) * 64 + cp0 + rg);
#pragma unroll
    for (int i = 0; i < 4; i++)
#pragma unroll
      for (int j = 0; j < 4; j++)
        acc[i][j] = __builtin_amdgcn_mfma_f32_16x16x32_bf16(af[i], bfr[j], acc[i][j], 0, 0, 0);
    // kk = 1
#pragma unroll
    for (int i = 0; i < 4; i++)
      af[i] = *(const bf16x8*)(As + (wm * 64 + i * 16 + row) * 64 + cp1 + rg);
#pragma unroll
    for (int j = 0; j < 4; j++)
      bfr[j] = *(const bf16x8*)(Bs + (wn * 64 + j * 16 + row) * 64 + cp1 + rg);
#pragma unroll
    for (int i = 0; i < 4; i++)
#pragma unroll
      for (int j = 0; j < 4; j++)
        acc[i][j] = __builtin_amdgcn_mfma_f32_16x16x32_bf16(af[i], bfr[j], acc[i][j], 0, 0, 0);
    __syncthreads();
  }

  // epilogue: C layout col=lane&15, row=(lane>>4)*4+reg
  int col_l = lane & 15, rquad = lane >> 4;
  unsigned short* xo = xrs + (size_t)by * ((size_t)N_NODES * D_HID);
#pragma unroll
  for (int i = 0; i < 4; i++) {
#pragma unroll
    for (int reg = 0; reg < 4; reg++) {
      int node = m0 + wm * 64 + i * 16 + rquad * 4 + reg;
      if (node < N_NODES) {
#pragma unroll
        for (int j = 0; j < 4; j++)
          xo[(size_t)node * D_HID + wn * 64 + j * 16 + col_l] = f2bf(acc[i][j][reg]);
      }
    }
  }
}

// ---- fallback GEMM (small ws): reg-staged, fp32 x with convert. B-source
// addressing unswizzles the wt layout (granule XOR + parity chunk swap).
__global__ __launch_bounds__(256) void k_gemm_f(
    const float* __restrict__ x, const unsigned short* __restrict__ wt,
    unsigned short* __restrict__ xrs, int mb) {
  __shared__ __align__(16) unsigned short As[64 * 40];
  __shared__ __align__(16) unsigned short Bs[256 * 40];

  int tid = threadIdx.x;
  int mat = mb + blockIdx.y;
  int m0 = blockIdx.x * 64;
  const unsigned short* wsec = wt + (size_t)mat * (D_HID * D_INP);
  int lane = tid & 63, w = tid >> 6;

  int ra = tid >> 2, ca = tid & 3, ca8 = ca * 8;
  int ra1 = ra & 1;
  int arow = m0 + ra; if (arow > N_NODES - 1) arow = N_NODES - 1;
  const float* apf = x + (size_t)arow * D_IN;
  const unsigned short* bgp = wsec + (size_t)ra * D_INP + (ca ^ ((ra >> 1) & 3)) * 8;
  unsigned short* al = As + ra * 40 + ca8;
  unsigned short* bl = Bs + ra * 40 + ca8;

  f32x4 acc[4][4];
#pragma unroll
  for (int i = 0; i < 4; i++)
#pragma unroll
    for (int j = 0; j < 4; j++) acc[i][j] = (f32x4){0.f, 0.f, 0.f, 0.f};

  float4 pa0 = *(const float4*)(apf + ca8);
  float4 pa1 = *(const float4*)(apf + ca8 + 4);
  int kb0 = ra1 * 32;                       // content chunk 0 position
  u32x4 pb0 = *(const u32x4*)(bgp + kb0);
  u32x4 pb1 = *(const u32x4*)(bgp + kb0 +  64 * D_INP);
  u32x4 pb2 = *(const u32x4*)(bgp + kb0 + 128 * D_INP);
  u32x4 pb3 = *(const u32x4*)(bgp + kb0 + 192 * D_INP);

  int row = lane & 15, quad = lane >> 4;
  for (int ks = 0; ks < 25; ks++) {
    if (ks < 24) {
      union { unsigned short us[8]; u32x4 v; } pk;
      pk.us[0] = f2bf(pa0.x); pk.us[1] = f2bf(pa0.y);
      pk.us[2] = f2bf(pa0.z); pk.us[3] = f2bf(pa0.w);
      pk.us[4] = f2bf(pa1.x); pk.us[5] = f2bf(pa1.y);
      pk.us[6] = f2bf(pa1.z); pk.us[7] = f2bf(pa1.w);
      *(u32x4*)al = pk.v;
    } else {
      float v0 = pa0.x, v1 = pa0.y, v2 = pa0.z, v3 = pa0.w;
      float v4 = pa1.x, v5 = pa1.y, v6 = pa1.z, v7 = pa1.w;
      if (ca8 == 16) { v0 = pa1.x; v1 = pa1.y; v2 = pa1.z; v3 = pa1.w;
                       v4 = 0.f; v5 = 0.f; v6 = 0.f; v7 = 0.f; }
      if (ca8 == 24) { v0 = 0.f; v1 = 0.f; v2 = 0.f; v3 = 0.f;
                       v4 = 0.f; v5 = 0.f; v6 = 0.f; v7 = 0.f; }
      union { unsigned short us[8]; u32x4 v; } pk;
      pk.us[0] = f2bf(v0); pk.us[1] = f2bf(v1); pk.us[2] = f2bf(v2); pk.us[3] = f2bf(v3);
      pk.us[4] = f2bf(v4); pk.us[5] = f2bf(v5); pk.us[6] = f2bf(v6); pk.us[7] = f2bf(v7);
      *(u32x4*)al = pk.v;
    }
    *(u32x4*)bl = pb0;
    *(u32x4*)(bl +  64 * 40) = pb1;
    *(u32x4*)(bl + 128 * 40) = pb2;
    *(u32x4*)(bl + 192 * 40) = pb3;
    __syncthreads();

    if (ks < 24) {
      int on = (ks + 1) * 32 + ca8;
      int lo = (on > 780) ? 780 : on;
      pa0 = *(const float4*)(apf + lo);
      pa1 = *(const float4*)(apf + lo + 4);
      int ko = ((ks + 1) ^ ra1) * 32;       // parity chunk swap
      pb0 = *(const u32x4*)(bgp + ko);
      pb1 = *(const u32x4*)(bgp + ko +  64 * D_INP);
      pb2 = *(const u32x4*)(bgp + ko + 128 * D_INP);
      pb3 = *(const u32x4*)(bgp + ko + 192 * D_INP);
    }

    bf16x8 af[4], bfr[4];
#pragma unroll
    for (int i = 0; i < 4; i++)
      af[i] = *(const bf16x8*)(As + (i * 16 + row) * 40 + quad * 8);
#pragma unroll
    for (int j = 0; j < 4; j++)
      bfr[j] = *(const bf16x8*)(Bs + (w * 64 + j * 16 + row) * 40 + quad * 8);
#pragma unroll
    for (int i = 0; i < 4; i++)
#pragma unroll
      for (int j = 0; j < 4; j++)
        acc[i][j] = __builtin_amdgcn_mfma_f32_16x16x32_bf16(af[i], bfr[j], acc[i][j], 0, 0, 0);
    __syncthreads();
  }

  int col_l = lane & 15, rquad = lane >> 4;
  unsigned short* xo = xrs + (size_t)blockIdx.y * ((size_t)N_NODES * D_HID);
#pragma unroll
  for (int i = 0; i < 4; i++) {
#pragma unroll
    for (int reg = 0; reg < 4; reg++) {
      int node = m0 + i * 16 + rquad * 4 + reg;
      if (node < N_NODES) {
#pragma unroll
        for (int j = 0; j < 4; j++)
          xo[(size_t)node * D_HID + w * 64 + j * 16 + col_l] = f2bf(acc[i][j][reg]);
      }
    }
  }
}

// ---- FULL-path aggregation: all 7 rels + root + bias + relu + fused layer-2
// in ONE pass (no h intermediate). One wave per node; xrs has 8 slabs.
// Epilogue v3 (proven): hv -> wave-local LDS, 8 lane-groups of 8 compute the
// 8 mats in parallel; lane sl owns dims {sl*4 + j*32} (conflict-free).
__global__ __launch_bounds__(256) void k_agg8(
    const unsigned short* __restrict__ xrs, const int* __restrict__ S,
    const int* __restrict__ cnt, const int* __restrict__ psrc,
    const float* __restrict__ b1, const float* __restrict__ w2rel,
    const float* __restrict__ w2root, float* __restrict__ y) {
  __shared__ float hsh[4][256];                 // 4 KB, one row per wave
  int wv = threadIdx.x >> 6;
  int n = blockIdx.x * 4 + wv;                  // grid exactly covers 50000
  int lane = threadIdx.x & 63;
  if (n >= N_NODES) return;

  // lanes 0..6 prefetch cnt/S for all rels; broadcast via shfl
  int c_l = 0, p_l = 0;
  if (lane < N_REL) {
    c_l = cnt[lane * N_NODES + n];
    p_l = S[lane * N_NODES + n];
  }

  f32x4 acc = (f32x4){0.f, 0.f, 0.f, 0.f};
#pragma unroll
  for (int r = 0; r < N_REL; r++) {
    int c = __shfl(c_l, r);
    if (c > 0) {
      int p = __shfl(p_l, r);
      const unsigned short* slab = xrs + (size_t)r * N_NODES * D_HID;
      f32x4 s = (f32x4){0.f, 0.f, 0.f, 0.f};
      int e = 0;
      for (; e + 1 < c; e += 2) {
        int s0 = psrc[p + e], s1 = psrc[p + e + 1];
        ushort4 g0 = *(const ushort4*)(slab + (size_t)s0 * D_HID + lane * 4);
        ushort4 g1 = *(const ushort4*)(slab + (size_t)s1 * D_HID + lane * 4);
        s += bf4(g0) + bf4(g1);
      }
      if (e < c) {
        int s0 = psrc[p + e];
        ushort4 g0 = *(const ushort4*)(slab + (size_t)s0 * D_HID + lane * 4);
        s += bf4(g0);
      }
      acc += s * (1.0f / (float)c);
    }
  }

  // root (slab 7) + bias + relu
  ushort4 gr = *(const ushort4*)(xrs + ((size_t)7 * N_NODES + n) * D_HID + lane * 4);
  acc += bf4(gr);
  f32x4 b = *(const f32x4*)(b1 + lane * 4);
  f32x4 hv;
  hv[0] = fmaxf(acc[0] + b[0], 0.f);
  hv[1] = fmaxf(acc[1] + b[1], 0.f);
  hv[2] = fmaxf(acc[2] + b[2], 0.f);
  hv[3] = fmaxf(acc[3] + b[3], 0.f);

  // wave-local LDS stash (same-wave DS ops are in-order; fence the compiler)
  *(f32x4*)&hsh[wv][lane * 4] = hv;
  __builtin_amdgcn_wave_barrier();

  // 8 lane-groups x 8 lanes: group m computes y[m][n][0..1]
  int m = lane >> 3, sl = lane & 7;
  const float* wp = (m < N_REL) ? (w2rel + m * (D_HID * 2)) : w2root;
  float d0 = 0.f, d1 = 0.f;
#pragma unroll
  for (int j = 0; j < 8; j++) {
    int db = sl * 4 + j * 32;                  // conflict-free partition
    f32x4 h4 = *(const f32x4*)&hsh[wv][db];
    f32x4 wa = *(const f32x4*)(wp + db * 2);
    f32x4 wb = *(const f32x4*)(wp + db * 2 + 4);
    d0 += h4[0] * wa[0] + h4[1] * wa[2] + h4[2] * wb[0] + h4[3] * wb[2];
    d1 += h4[0] * wa[1] + h4[1] * wa[3] + h4[2] * wb[1] + h4[3] * wb[3];
  }
  d0 += __shfl_down(d0, 1); d1 += __shfl_down(d1, 1);
  d0 += __shfl_down(d0, 2); d1 += __shfl_down(d1, 2);
  d0 += __shfl_down(d0, 4); d1 += __shfl_down(d1, 4);
  if (sl == 0) {
    y[(size_t)m * (N_NODES * 2) + n * 2]     = d0;
    y[(size_t)m * (N_NODES * 2) + n * 2 + 1] = d1;
  }
}

// ---- fallback aggregation (4-pass, h intermediate) ----
__global__ __launch_bounds__(256) void k_agg(
    const unsigned short* __restrict__ xrs, const int* __restrict__ S,
    const int* __restrict__ cnt, const int* __restrict__ psrc,
    float* __restrict__ h, const float* __restrict__ b1,
    const float* __restrict__ w2rel, const float* __restrict__ w2root,
    float* __restrict__ y, int r0, int pass) {
  int n = blockIdx.x * 4 + (threadIdx.x >> 6);
  int lane = threadIdx.x & 63;
  if (n >= N_NODES) return;
  f32x4 acc;
  if (pass == 0) acc = (f32x4){0.f, 0.f, 0.f, 0.f};
  else acc = *(const f32x4*)(h + (size_t)n * D_HID + lane * 4);

  int nr = (pass < 3) ? 2 : 1;
  for (int rr = 0; rr < nr; rr++) {
    int bin = (r0 + rr) * N_NODES + n;
    int c = cnt[bin];
    if (c > 0) {
      int p = S[bin];
      f32x4 s = (f32x4){0.f, 0.f, 0.f, 0.f};
      int e = 0;
      for (; e + 1 < c; e += 2) {
        int s0 = psrc[p + e], s1 = psrc[p + e + 1];
        ushort4 g0 = *(const ushort4*)(xrs + ((size_t)rr * N_NODES + s0) * D_HID + lane * 4);
        ushort4 g1 = *(const ushort4*)(xrs + ((size_t)rr * N_NODES + s1) * D_HID + lane * 4);
        s += bf4(g0) + bf4(g1);
      }
      if (e < c) {
        int s0 = psrc[p + e];
        ushort4 g0 = *(const ushort4*)(xrs + ((size_t)rr * N_NODES + s0) * D_HID + lane * 4);
        s += bf4(g0);
      }
      acc += s * (1.0f / (float)c);
    }
  }

  if (pass < 3) {
    *(f32x4*)(h + (size_t)n * D_HID + lane * 4) = acc;
    return;
  }

  ushort4 gr = *(const ushort4*)(xrs + ((size_t)1 * N_NODES + n) * D_HID + lane * 4);
  acc += bf4(gr);
  f32x4 b = *(const f32x4*)(b1 + lane * 4);
  f32x4 hv;
  hv[0] = fmaxf(acc[0] + b[0], 0.f);
  hv[1] = fmaxf(acc[1] + b[1], 0.f);
  hv[2] = fmaxf(acc[2] + b[2], 0.f);
  hv[3] = fmaxf(acc[3] + b[3], 0.f);

#pragma unroll
  for (int m = 0; m < 8; m++) {
    const float* wp = (m < N_REL) ? (w2rel + m * (D_HID * 2)) : w2root;
    f32x4 wa = *(const f32x4*)(wp + lane * 8);
    f32x4 wb = *(const f32x4*)(wp + lane * 8 + 4);
    float d0 = hv[0] * wa[0] + hv[1] * wa[2] + hv[2] * wb[0] + hv[3] * wb[2];
    float d1 = hv[0] * wa[1] + hv[1] * wa[3] + hv[2] * wb[1] + hv[3] * wb[3];
#pragma unroll
    for (int off = 32; off > 0; off >>= 1) {
      d0 += __shfl_down(d0, off);
      d1 += __shfl_down(d1, off);
    }
    if (lane == 0) {
      y[(size_t)m * (N_NODES * 2) + n * 2]     = d0;
      y[(size_t)m * (N_NODES * 2) + n * 2 + 1] = d1;
    }
  }
}

// ---- layer-2 aggregation: thread per bin (mean over bin) + root/bias threads ----
__global__ void k_out(const float* __restrict__ y, const float* __restrict__ b2,
                      const int* __restrict__ cnt, const int* __restrict__ S,
                      const int* __restrict__ psrc, float* __restrict__ out) {
  int t = blockIdx.x * blockDim.x + threadIdx.x;
  if (t < NBINS) {
    int c = cnt[t];
    if (c == 0) return;
    int p = S[t];
    int r = t / N_NODES;
    int i = t - r * N_NODES;
    const float* yr = y + (size_t)r * (N_NODES * 2);
    float s0 = 0.f, s1 = 0.f;
    for (int e = 0; e < c; e++) {
      int sc = psrc[p + e];
      float2 v = *(const float2*)(yr + sc * 2);
      s0 += v.x; s1 += v.y;
    }
    float is = 1.0f / (float)c;
    atomicAdd(out + (size_t)i * 2,     s0 * is);
    atomicAdd(out + (size_t)i * 2 + 1, s1 * is);
  } else if (t < NBINS + N_NODES) {
    int i = t - NBINS;
    float2 v = *(const float2*)(y + (size_t)N_REL * (N_NODES * 2) + i * 2);
    atomicAdd(out + (size_t)i * 2,     v.x + b2[0]);
    atomicAdd(out + (size_t)i * 2 + 1, v.y + b2[1]);
  }
}

// ---- fallback workspace layout (D_INP=832); total 199,611,968 w/ xb ----
#define OFF_WT   0u            // 8*256*832*2 = 3,407,872
#define OFF_XRS  3407872u      // 2 slabs     = 51,200,000
#define OFF_H    54607872u     // 51,200,000
#define OFF_CNT  105807872u    // 1,400,000
#define OFF_RANK 107207872u    // 1,400,000
#define OFF_S    108607872u    // 1,400,000
#define OFF_PSRC 110007872u    // 3,200,000
#define OFF_Y    113207872u    // 3,200,000
#define OFF_BSUM 116407872u    // 2048
#define OFF_BOFF 116409920u    // 2048
#define OFF_XB   116411968u    // 50000*832*2 = 83,200,000
#define WS_NEED_XB 199611968ull

// ---- FULL layout: 8-slab xrs, no h; total 302,011,968 ----
#define F_OFF_WT   0u            // 3,407,872
#define F_OFF_XRS  3407872u      // 8*50000*256*2 = 204,800,000
#define F_OFF_CNT  208207872u    // 1,400,000
#define F_OFF_RANK 209607872u    // 1,400,000
#define F_OFF_S    211007872u    // 1,400,000
#define F_OFF_PSRC 212407872u    // 3,200,000
#define F_OFF_Y    215607872u    // 3,200,000
#define F_OFF_BSUM 218807872u    // 2048
#define F_OFF_BOFF 218809920u    // 2048
#define F_OFF_XB   218811968u    // 83,200,000
#define WS_NEED_FULL 302011968ull

extern "C" void kernel_launch(void* const* d_in, const int* in_sizes, int n_in,
                              void* d_out, int out_size, void* d_ws, size_t ws_size,
                              hipStream_t stream) {
  const float* x      = (const float*)d_in[0];
  const int*   eidx   = (const int*)d_in[1];
  const int*   etype  = (const int*)d_in[2];
  const float* w1rel  = (const float*)d_in[3];
  const float* w1root = (const float*)d_in[4];
  const float* b1     = (const float*)d_in[5];
  const float* w2rel  = (const float*)d_in[6];
  const float* w2root = (const float*)d_in[7];
  const float* b2     = (const float*)d_in[8];
  float* out = (float*)d_out;
  char* ws = (char*)d_ws;
  const int* esrc = eidx;
  const int* edst = eidx + N_EDGES;

  const bool full = (ws_size >= WS_NEED_FULL);
  const bool big  = !full && (ws_size >= WS_NEED_XB);

  hipMemsetAsync(d_out, 0, (size_t)out_size * sizeof(float), stream);

  if (full) {
    unsigned short* wt  = (unsigned short*)(ws + F_OFF_WT);
    unsigned short* xrs = (unsigned short*)(ws + F_OFF_XRS);
    int*   cnt  = (int*)(ws + F_OFF_CNT);
    int*   rank = (int*)(ws + F_OFF_RANK);
    int*   S    = (int*)(ws + F_OFF_S);
    int*   psrc = (int*)(ws + F_OFF_PSRC);
    float* y    = (float*)(ws + F_OFF_Y);
    int*   bsum = (int*)(ws + F_OFF_BSUM);
    int*   boff = (int*)(ws + F_OFF_BOFF);
    unsigned short* xb = (unsigned short*)(ws + F_OFF_XB);

    hipMemsetAsync(ws + F_OFF_CNT, 0, 2800000u, stream);       // cnt + rank

    k_conv_w<<<8 * 26, 256, 0, stream>>>(w1rel, w1root, wt);
    k_xbf<<<(N_NODES * 104 + 255) / 256, 256, 0, stream>>>(x, xb);
    k_count<<<(N_EDGES + 255) / 256, 256, 0, stream>>>(etype, edst, cnt);
    k_scan1<<<NSCANB, 256, 0, stream>>>(cnt, bsum);
    k_scan2<<<1, 512, 0, stream>>>(bsum, boff);
    k_scan3<<<NSCANB, 256, 0, stream>>>(cnt, boff, S);
    k_scatter<<<(N_EDGES + 255) / 256, 256, 0, stream>>>(etype, edst, esrc, S, rank, psrc);

    k_gemm_g<1, 8><<<NXTILE * 8, 512, 0, stream>>>(xb, wt, xrs, 0);
    k_agg8<<<(N_NODES + 3) / 4, 256, 0, stream>>>(xrs, S, cnt, psrc,
                                                  b1, w2rel, w2root, y);
    k_out<<<(NBINS + N_NODES + 255) / 256, 256, 0, stream>>>(y, b2, cnt, S, psrc, out);
    return;
  }

  unsigned short* wt  = (unsigned short*)(ws + OFF_WT);
  unsigned short* xrs = (unsigned short*)(ws + OFF_XRS);
  float* h    = (float*)(ws + OFF_H);
  int*   cnt  = (int*)(ws + OFF_CNT);
  int*   rank = (int*)(ws + OFF_RANK);
  int*   S    = (int*)(ws + OFF_S);
  int*   psrc = (int*)(ws + OFF_PSRC);
  float* y    = (float*)(ws + OFF_Y);
  int*   bsum = (int*)(ws + OFF_BSUM);
  int*   boff = (int*)(ws + OFF_BOFF);
  unsigned short* xb = (unsigned short*)(ws + OFF_XB);

  hipMemsetAsync(ws + OFF_CNT, 0, 2800000u, stream);           // cnt + rank

  k_conv_w<<<8 * 26, 256, 0, stream>>>(w1rel, w1root, wt);
  if (big)
    k_xbf<<<(N_NODES * 104 + 255) / 256, 256, 0, stream>>>(x, xb);
  k_count<<<(N_EDGES + 255) / 256, 256, 0, stream>>>(etype, edst, cnt);
  k_scan1<<<NSCANB, 256, 0, stream>>>(cnt, bsum);
  k_scan2<<<1, 512, 0, stream>>>(bsum, boff);
  k_scan3<<<NSCANB, 256, 0, stream>>>(cnt, boff, S);
  k_scatter<<<(N_EDGES + 255) / 256, 256, 0, stream>>>(etype, edst, esrc, S, rank, psrc);

  for (int p = 0; p < 4; p++) {
    if (big)
      k_gemm_g<0, 2><<<dim3(NXTILE, 2), 512, 0, stream>>>(xb, wt, xrs, 2 * p);
    else
      k_gemm_f<<<dim3(782, 2), 256, 0, stream>>>(x, wt, xrs, 2 * p);
    k_agg<<<(N_NODES + 3) / 4, 256, 0, stream>>>(xrs, S, cnt, psrc, h,
                                                 b1, w2rel, w2root, y, 2 * p, p);
  }

  k_out<<<(NBINS + N_NODES + 255) / 256, 256, 0, stream>>>(y, b2, cnt, S, psrc, out);
}

// Round 8
// 666.435 us; speedup vs baseline: 1.0683x; 1.0246x over previous
//
#include <hip/hip_runtime.h>
#include <hip/hip_bf16.h>
#include <stdint.h>

#define N_NODES 50000
#define N_EDGES 800000
#define D_IN    788
#define NCHUNK  26       // K padded to 26*32 = 832 (BK=64 = 2 chunks/step)
#define CS_X    (N_NODES * 32)   // xb chunk stride (elements)
#define CS_W    (256 * 32)       // wt chunk stride (elements) = 8192
#define D_HID   256
#define N_REL   7
#define NBINS   (N_REL * N_NODES)   // 350000
#define NSCANB  342                 // ceil(350000/1024)
#define NXTILE  391                 // ceil(50000/128)

typedef __attribute__((ext_vector_type(8))) short bf16x8;
typedef __attribute__((ext_vector_type(4))) float f32x4;
typedef __attribute__((ext_vector_type(4))) unsigned int u32x4;

// RNE float->bf16 via compiler cast (emits v_cvt_pk_bf16_f32 when pairable)
__device__ __forceinline__ unsigned short f2bf(float f) {
  union { __hip_bfloat16 h; unsigned short u; } v;
  v.h = __float2bfloat16(f);
  return v.u;
}

__device__ __forceinline__ f32x4 bf4(ushort4 g) {
  union { unsigned int u; float f; } a, b, c, d;
  a.u = (unsigned)g.x << 16; b.u = (unsigned)g.y << 16;
  c.u = (unsigned)g.z << 16; d.u = (unsigned)g.w << 16;
  return (f32x4){a.f, b.f, c.f, d.f};
}

// async global->LDS, 16B per lane (wave-uniform LDS base + lane*16)
#define GLOAD16(g, l) __builtin_amdgcn_global_load_lds(                      \
    (const __attribute__((address_space(1))) unsigned int*)(g),              \
    (__attribute__((address_space(3))) unsigned int*)(l), 16, 0, 0)

// ---- Swizzle convention (PROVEN 0-conflict in rounds 3-6) ----
// Chunk-major layouts: xb[chunk][node][32], wt[mat][chunk][o][32].
// Within each 32-elem chunk (4 granules of 8), content granule g is stored at
// position g ^ ((row>>1)&3). Reader (stride-32 LDS tile) unswizzles with the
// same XOR -> ds_read_b128 fragments hit all 32 banks (measured 0 conflicts).
// No parity-chunk swap (the round-7 128B-stride layout conflicted, 2.08e7).

// ---- weights -> bf16, [mat][chunk][o][32] swizzled, coalesced reads ----
__global__ void k_conv_w(const float* __restrict__ w_rel, const float* __restrict__ w_root,
                         unsigned short* __restrict__ wt) {
  int b = blockIdx.x;                 // grid = 8 mats * 26 chunks
  int m = b / NCHUNK, chunk = b % NCHUNK;
  int o = threadIdx.x;                // 256 threads = one per output col
  const float* src = (m < N_REL) ? (w_rel + (size_t)m * D_IN * D_HID) : w_root;
  int k0 = chunk * 32;

  unsigned short v[32];
#pragma unroll
  for (int kk = 0; kk < 32; kk++) {
    int k = k0 + kk;
    v[kk] = (k < D_IN) ? f2bf(src[(size_t)k * D_HID + o]) : (unsigned short)0;
  }

  unsigned short* dst = wt + (size_t)m * (NCHUNK * CS_W) + (size_t)chunk * CS_W + o * 32;
  int sw = (o >> 1) & 3;
#pragma unroll
  for (int g = 0; g < 4; g++) {       // content granule g -> position g^sw
    union { unsigned short us[8]; u32x4 u; } pk;
#pragma unroll
    for (int j = 0; j < 8; j++) pk.us[j] = v[g * 8 + j];
    *(u32x4*)(dst + (g ^ sw) * 8) = pk.u;
  }
}

// ---- x -> bf16, chunk-major [chunk][node][32], swizzled, pad zeroed ----
__global__ void k_xbf(const float* __restrict__ x, unsigned short* __restrict__ xb) {
  int t = blockIdx.x * blockDim.x + threadIdx.x;   // one thread per 8-elem granule
  if (t >= NCHUNK * N_NODES * 4) return;
  int chunk = t / (N_NODES * 4);
  int rem = t - chunk * (N_NODES * 4);
  int n = rem >> 2, p = rem & 3;
  int g = p ^ ((n >> 1) & 3);
  int c = chunk * 32 + g * 8;         // content k0
  union { unsigned short us[8]; u32x4 v; } pk;
  if (c + 7 < D_IN) {
    float4 a = *(const float4*)(x + (size_t)n * D_IN + c);
    float4 b = *(const float4*)(x + (size_t)n * D_IN + c + 4);
    pk.us[0] = f2bf(a.x); pk.us[1] = f2bf(a.y); pk.us[2] = f2bf(a.z); pk.us[3] = f2bf(a.w);
    pk.us[4] = f2bf(b.x); pk.us[5] = f2bf(b.y); pk.us[6] = f2bf(b.z); pk.us[7] = f2bf(b.w);
  } else {
#pragma unroll
    for (int j = 0; j < 8; j++)
      pk.us[j] = (c + j < D_IN) ? f2bf(x[(size_t)n * D_IN + c + j]) : (unsigned short)0;
  }
  *(u32x4*)(xb + (size_t)chunk * CS_X + (size_t)n * 32 + p * 8) = pk.v;
}

// ---- per-(rel,dst) edge counts ----
__global__ void k_count(const int* __restrict__ etype, const int* __restrict__ edst,
                        int* __restrict__ cnt) {
  int t = blockIdx.x * blockDim.x + threadIdx.x;
  if (t >= N_EDGES) return;
  atomicAdd(&cnt[etype[t] * N_NODES + edst[t]], 1);
}

// ==== exclusive scan of cnt[350000] -> S (3 kernels) ====
__global__ void k_scan1(const int* __restrict__ cnt, int* __restrict__ bsum) {
  __shared__ int wsh[4];
  int b = blockIdx.x, tid = threadIdx.x;
  int base = b * 1024 + tid * 4;
  int4 v = {0, 0, 0, 0};
  if (base + 3 < NBINS) v = *(const int4*)(cnt + base);
  else { for (int i = 0; i < 4; i++) if (base + i < NBINS) ((int*)&v)[i] = cnt[base + i]; }
  int s = v.x + v.y + v.z + v.w;
  for (int o = 32; o > 0; o >>= 1) s += __shfl_down(s, o);
  if ((tid & 63) == 0) wsh[tid >> 6] = s;
  __syncthreads();
  if (tid == 0) bsum[b] = wsh[0] + wsh[1] + wsh[2] + wsh[3];
}

__global__ void k_scan2(const int* __restrict__ bsum, int* __restrict__ boff) {
  __shared__ int tmp[512];
  int tid = threadIdx.x;
  int mine = (tid < NSCANB) ? bsum[tid] : 0;
  tmp[tid] = mine;
  __syncthreads();
  for (int o = 1; o < 512; o <<= 1) {
    int v = (tid >= o) ? tmp[tid - o] : 0;
    __syncthreads();
    tmp[tid] += v;
    __syncthreads();
  }
  if (tid < NSCANB) boff[tid] = tmp[tid] - mine;   // exclusive
}

__global__ void k_scan3(const int* __restrict__ cnt, const int* __restrict__ boff,
                        int* __restrict__ S) {
  __shared__ int wsum[4];
  int b = blockIdx.x, tid = threadIdx.x;
  int base = b * 1024 + tid * 4;
  int4 v = {0, 0, 0, 0};
  if (base + 3 < NBINS) v = *(const int4*)(cnt + base);
  else { for (int i = 0; i < 4; i++) if (base + i < NBINS) ((int*)&v)[i] = cnt[base + i]; }
  int s = v.x + v.y + v.z + v.w;
  int lane = tid & 63, w = tid >> 6;
  int sc = s;
  for (int o = 1; o < 64; o <<= 1) { int u = __shfl_up(sc, o); if (lane >= o) sc += u; }
  if (lane == 63) wsum[w] = sc;
  __syncthreads();
  int wbase = 0;
  for (int i = 0; i < w; i++) wbase += wsum[i];
  int excl = boff[b] + wbase + sc - s;
  int o0 = excl, o1 = excl + v.x, o2 = o1 + v.y, o3 = o2 + v.z;
  if (base + 3 < NBINS) { int4 o4 = {o0, o1, o2, o3}; *(int4*)(S + base) = o4; }
  else {
    if (base     < NBINS) S[base]     = o0;
    if (base + 1 < NBINS) S[base + 1] = o1;
    if (base + 2 < NBINS) S[base + 2] = o2;
    if (base + 3 < NBINS) S[base + 3] = o3;
  }
}

// ---- scatter edge SOURCES into bin-sorted order ----
__global__ void k_scatter(const int* __restrict__ etype, const int* __restrict__ edst,
                          const int* __restrict__ esrc, const int* __restrict__ S,
                          int* __restrict__ rank, int* __restrict__ psrc) {
  int t = blockIdx.x * blockDim.x + threadIdx.x;
  if (t >= N_EDGES) return;
  int bin = etype[t] * N_NODES + edst[t];
  int r = atomicAdd(&rank[bin], 1);
  psrc[S[bin] + r] = esrc[t];
}

// ---- bf16 GEMM v4: 128x256 tile, 8 waves (2M x 4N, each 64x64), BK=64
// (13 K-steps, halved barrier count — round-7 win) BUT with LDS as two
// stride-32 sub-tiles [kk][rows][32] (round-3's PROVEN 0-conflict read
// pattern; round-7's 128B-stride rows conflicted at 2.08e7).
// Chunk-major global layouts make each staged chunk contiguous (A: 8KB,
// B: 16KB per chunk) -> perfectly coalesced GLOAD waves.
// SWZ=1: XCD-chunked bijection so NMAT col-blocks sharing an A-tile run
// consecutively on one XCD (A-tile L2 reuse).
template<int SWZ, int NMAT>
__global__ __launch_bounds__(512) void k_gemm_g(
    const unsigned short* __restrict__ xb, const unsigned short* __restrict__ wt,
    unsigned short* __restrict__ xrs, int mb) {
  __shared__ __align__(16) unsigned short As[2 * 128 * 32];   // 16 KB
  __shared__ __align__(16) unsigned short Bs[2 * 256 * 32];   // 32 KB

  int tid = threadIdx.x;
  int bx, by;
  if (SWZ) {
    int b = blockIdx.x;                       // grid = NXTILE * NMAT (1D), %8==0
    int l = (b % 8) * (NXTILE * NMAT / 8) + b / 8;
    bx = l / NMAT; by = l % NMAT;             // consecutive l share bx -> A reuse
  } else {
    bx = blockIdx.x; by = blockIdx.y;
  }
  int mat = mb + by;
  int m0 = bx * 128;
  const unsigned short* wsec = wt + (size_t)mat * (NCHUNK * CS_W);
  int lane = tid & 63, w = tid >> 6;
  int wm = w >> 2, wn = w & 3;

  // staging: thread covers (row = tid>>2, granule pos = tid&3) of each sub-tile
  int sr = tid >> 2, sg = (tid & 3) * 8;
  int arow = m0 + sr; if (arow > N_NODES - 1) arow = N_NODES - 1;
  const unsigned short* axb = xb + (size_t)arow * 32 + sg;   // + chunk*CS_X
  const unsigned short* bw  = wsec + (size_t)sr * 32 + sg;   // + chunk*CS_W
  unsigned short* al0 = As + tid * 8;            // [kk0][sr][sg]
  unsigned short* al1 = As + 4096 + tid * 8;     // [kk1][sr][sg]
  unsigned short* bl0 = Bs + tid * 8;            // [kk0][rows 0-127]
  unsigned short* bl1 = Bs + 4096 + tid * 8;     // [kk0][rows 128-255]
  unsigned short* bl2 = Bs + 8192 + tid * 8;     // [kk1][rows 0-127]
  unsigned short* bl3 = Bs + 12288 + tid * 8;    // [kk1][rows 128-255]

  f32x4 acc[4][4];
#pragma unroll
  for (int i = 0; i < 4; i++)
#pragma unroll
    for (int j = 0; j < 4; j++) acc[i][j] = (f32x4){0.f, 0.f, 0.f, 0.f};

  int row = lane & 15, quad = lane >> 4;
  int rg = (quad ^ ((row >> 1) & 3)) * 8;        // granule unswizzle (proven)

  for (int ks = 0; ks < 13; ks++) {
    size_t cx = (size_t)(2 * ks) * CS_X;
    int    cw = 2 * ks * CS_W;
    GLOAD16(axb + cx, al0);
    GLOAD16(axb + cx + CS_X, al1);
    GLOAD16(bw + cw, bl0);
    GLOAD16(bw + cw + 4096, bl1);
    GLOAD16(bw + cw + CS_W, bl2);
    GLOAD16(bw + cw + CS_W + 4096, bl3);
    __syncthreads();                             // drains vmcnt before barrier

#pragma unroll
    for (int kk = 0; kk < 2; kk++) {
      const unsigned short* Ac = As + kk * 4096;
      const unsigned short* Bc = Bs + kk * 8192;
      bf16x8 af[4], bfr[4];
#pragma unroll
      for (int i = 0; i < 4; i++)
        af[i] = *(const bf16x8*)(Ac + (wm * 64 + i * 16 + row) * 32 + rg);
#pragma unroll
      for (int j = 0; j < 4; j++)
        bfr[j] = *(const bf16x8*)(Bc + (wn * 64 + j * 16 + row) * 32 + rg);
#pragma unroll
      for (int i = 0; i < 4; i++)
#pragma unroll
        for (int j = 0; j < 4; j++)
          acc[i][j] = __builtin_amdgcn_mfma_f32_16x16x32_bf16(af[i], bfr[j], acc[i][j], 0, 0, 0);
    }
    __syncthreads();
  }

  // epilogue: C layout col=lane&15, row=(lane>>4)*4+reg
  int col_l = lane & 15, rquad = lane >> 4;
  unsigned short* xo = xrs + (size_t)by * ((size_t)N_NODES * D_HID);
#pragma unroll
  for (int i = 0; i < 4; i++) {
#pragma unroll
    for (int reg = 0; reg < 4; reg++) {
      int node = m0 + wm * 64 + i * 16 + rquad * 4 + reg;
      if (node < N_NODES) {
#pragma unroll
        for (int j = 0; j < 4; j++)
          xo[(size_t)node * D_HID + wn * 64 + j * 16 + col_l] = f2bf(acc[i][j][reg]);
      }
    }
  }
}

// ---- fallback GEMM (small ws): reg-staged, fp32 x with convert. B-source
// addressing for the chunk-major swizzled wt layout.
__global__ __launch_bounds__(256) void k_gemm_f(
    const float* __restrict__ x, const unsigned short* __restrict__ wt,
    unsigned short* __restrict__ xrs, int mb) {
  __shared__ __align__(16) unsigned short As[64 * 40];
  __shared__ __align__(16) unsigned short Bs[256 * 40];

  int tid = threadIdx.x;
  int mat = mb + blockIdx.y;
  int m0 = blockIdx.x * 64;
  const unsigned short* wsec = wt + (size_t)mat * (NCHUNK * CS_W);
  int lane = tid & 63, w = tid >> 6;

  int ra = tid >> 2, ca = tid & 3, ca8 = ca * 8;
  int arow = m0 + ra; if (arow > N_NODES - 1) arow = N_NODES - 1;
  const float* apf = x + (size_t)arow * D_IN;
  // content granule ca lives at position ca ^ ((ra>>1)&3) within row ra's chunk
  const unsigned short* bgp = wsec + (size_t)ra * 32 + (ca ^ ((ra >> 1) & 3)) * 8;
  unsigned short* al = As + ra * 40 + ca8;
  unsigned short* bl = Bs + ra * 40 + ca8;

  f32x4 acc[4][4];
#pragma unroll
  for (int i = 0; i < 4; i++)
#pragma unroll
    for (int j = 0; j < 4; j++) acc[i][j] = (f32x4){0.f, 0.f, 0.f, 0.f};

  float4 pa0 = *(const float4*)(apf + ca8);
  float4 pa1 = *(const float4*)(apf + ca8 + 4);
  u32x4 pb0 = *(const u32x4*)(bgp);
  u32x4 pb1 = *(const u32x4*)(bgp +  64 * 32);
  u32x4 pb2 = *(const u32x4*)(bgp + 128 * 32);
  u32x4 pb3 = *(const u32x4*)(bgp + 192 * 32);

  int row = lane & 15, quad = lane >> 4;
  for (int ks = 0; ks < 25; ks++) {
    if (ks < 24) {
      union { unsigned short us[8]; u32x4 v; } pk;
      pk.us[0] = f2bf(pa0.x); pk.us[1] = f2bf(pa0.y);
      pk.us[2] = f2bf(pa0.z); pk.us[3] = f2bf(pa0.w);
      pk.us[4] = f2bf(pa1.x); pk.us[5] = f2bf(pa1.y);
      pk.us[6] = f2bf(pa1.z); pk.us[7] = f2bf(pa1.w);
      *(u32x4*)al = pk.v;
    } else {
      float v0 = pa0.x, v1 = pa0.y, v2 = pa0.z, v3 = pa0.w;
      float v4 = pa1.x, v5 = pa1.y, v6 = pa1.z, v7 = pa1.w;
      if (ca8 == 16) { v0 = pa1.x; v1 = pa1.y; v2 = pa1.z; v3 = pa1.w;
                       v4 = 0.f; v5 = 0.f; v6 = 0.f; v7 = 0.f; }
      if (ca8 == 24) { v0 = 0.f; v1 = 0.f; v2 = 0.f; v3 = 0.f;
                       v4 = 0.f; v5 = 0.f; v6 = 0.f; v7 = 0.f; }
      union { unsigned short us[8]; u32x4 v; } pk;
      pk.us[0] = f2bf(v0); pk.us[1] = f2bf(v1); pk.us[2] = f2bf(v2); pk.us[3] = f2bf(v3);
      pk.us[4] = f2bf(v4); pk.us[5] = f2bf(v5); pk.us[6] = f2bf(v6); pk.us[7] = f2bf(v7);
      *(u32x4*)al = pk.v;
    }
    *(u32x4*)bl = pb0;
    *(u32x4*)(bl +  64 * 40) = pb1;
    *(u32x4*)(bl + 128 * 40) = pb2;
    *(u32x4*)(bl + 192 * 40) = pb3;
    __syncthreads();

    if (ks < 24) {
      int on = (ks + 1) * 32 + ca8;
      int lo = (on > 780) ? 780 : on;
      pa0 = *(const float4*)(apf + lo);
      pa1 = *(const float4*)(apf + lo + 4);
      int ko = (ks + 1) * CS_W;             // next content chunk
      pb0 = *(const u32x4*)(bgp + ko);
      pb1 = *(const u32x4*)(bgp + ko +  64 * 32);
      pb2 = *(const u32x4*)(bgp + ko + 128 * 32);
      pb3 = *(const u32x4*)(bgp + ko + 192 * 32);
    }

    bf16x8 af[4], bfr[4];
#pragma unroll
    for (int i = 0; i < 4; i++)
      af[i] = *(const bf16x8*)(As + (i * 16 + row) * 40 + quad * 8);
#pragma unroll
    for (int j = 0; j < 4; j++)
      bfr[j] = *(const bf16x8*)(Bs + (w * 64 + j * 16 + row) * 40 + quad * 8);
#pragma unroll
    for (int i = 0; i < 4; i++)
#pragma unroll
      for (int j = 0; j < 4; j++)
        acc[i][j] = __builtin_amdgcn_mfma_f32_16x16x32_bf16(af[i], bfr[j], acc[i][j], 0, 0, 0);
    __syncthreads();
  }

  int col_l = lane & 15, rquad = lane >> 4;
  unsigned short* xo = xrs + (size_t)blockIdx.y * ((size_t)N_NODES * D_HID);
#pragma unroll
  for (int i = 0; i < 4; i++) {
#pragma unroll
    for (int reg = 0; reg < 4; reg++) {
      int node = m0 + i * 16 + rquad * 4 + reg;
      if (node < N_NODES) {
#pragma unroll
        for (int j = 0; j < 4; j++)
          xo[(size_t)node * D_HID + w * 64 + j * 16 + col_l] = f2bf(acc[i][j][reg]);
      }
    }
  }
}

// ---- FULL-path aggregation: all 7 rels + root + bias + relu + fused layer-2
// in ONE pass (no h intermediate). One wave per node; xrs has 8 slabs.
// Epilogue v3 (proven): hv -> wave-local LDS, 8 lane-groups of 8 compute the
// 8 mats in parallel; lane sl owns dims {sl*4 + j*32} (conflict-free).
__global__ __launch_bounds__(256) void k_agg8(
    const unsigned short* __restrict__ xrs, const int* __restrict__ S,
    const int* __restrict__ cnt, const int* __restrict__ psrc,
    const float* __restrict__ b1, const float* __restrict__ w2rel,
    const float* __restrict__ w2root, float* __restrict__ y) {
  __shared__ float hsh[4][256];                 // 4 KB, one row per wave
  int wv = threadIdx.x >> 6;
  int n = blockIdx.x * 4 + wv;                  // grid exactly covers 50000
  int lane = threadIdx.x & 63;
  if (n >= N_NODES) return;

  // lanes 0..6 prefetch cnt/S for all rels; broadcast via shfl
  int c_l = 0, p_l = 0;
  if (lane < N_REL) {
    c_l = cnt[lane * N_NODES + n];
    p_l = S[lane * N_NODES + n];
  }

  f32x4 acc = (f32x4){0.f, 0.f, 0.f, 0.f};
#pragma unroll
  for (int r = 0; r < N_REL; r++) {
    int c = __shfl(c_l, r);
    if (c > 0) {
      int p = __shfl(p_l, r);
      const unsigned short* slab = xrs + (size_t)r * N_NODES * D_HID;
      f32x4 s = (f32x4){0.f, 0.f, 0.f, 0.f};
      int e = 0;
      for (; e + 1 < c; e += 2) {
        int s0 = psrc[p + e], s1 = psrc[p + e + 1];
        ushort4 g0 = *(const ushort4*)(slab + (size_t)s0 * D_HID + lane * 4);
        ushort4 g1 = *(const ushort4*)(slab + (size_t)s1 * D_HID + lane * 4);
        s += bf4(g0) + bf4(g1);
      }
      if (e < c) {
        int s0 = psrc[p + e];
        ushort4 g0 = *(const ushort4*)(slab + (size_t)s0 * D_HID + lane * 4);
        s += bf4(g0);
      }
      acc += s * (1.0f / (float)c);
    }
  }

  // root (slab 7) + bias + relu
  ushort4 gr = *(const ushort4*)(xrs + ((size_t)7 * N_NODES + n) * D_HID + lane * 4);
  acc += bf4(gr);
  f32x4 b = *(const f32x4*)(b1 + lane * 4);
  f32x4 hv;
  hv[0] = fmaxf(acc[0] + b[0], 0.f);
  hv[1] = fmaxf(acc[1] + b[1], 0.f);
  hv[2] = fmaxf(acc[2] + b[2], 0.f);
  hv[3] = fmaxf(acc[3] + b[3], 0.f);

  // wave-local LDS stash (same-wave DS ops are in-order; fence the compiler)
  *(f32x4*)&hsh[wv][lane * 4] = hv;
  __builtin_amdgcn_wave_barrier();

  // 8 lane-groups x 8 lanes: group m computes y[m][n][0..1]
  int m = lane >> 3, sl = lane & 7;
  const float* wp = (m < N_REL) ? (w2rel + m * (D_HID * 2)) : w2root;
  float d0 = 0.f, d1 = 0.f;
#pragma unroll
  for (int j = 0; j < 8; j++) {
    int db = sl * 4 + j * 32;                  // conflict-free partition
    f32x4 h4 = *(const f32x4*)&hsh[wv][db];
    f32x4 wa = *(const f32x4*)(wp + db * 2);
    f32x4 wb = *(const f32x4*)(wp + db * 2 + 4);
    d0 += h4[0] * wa[0] + h4[1] * wa[2] + h4[2] * wb[0] + h4[3] * wb[2];
    d1 += h4[0] * wa[1] + h4[1] * wa[3] + h4[2] * wb[1] + h4[3] * wb[3];
  }
  d0 += __shfl_down(d0, 1); d1 += __shfl_down(d1, 1);
  d0 += __shfl_down(d0, 2); d1 += __shfl_down(d1, 2);
  d0 += __shfl_down(d0, 4); d1 += __shfl_down(d1, 4);
  if (sl == 0) {
    y[(size_t)m * (N_NODES * 2) + n * 2]     = d0;
    y[(size_t)m * (N_NODES * 2) + n * 2 + 1] = d1;
  }
}

// ---- fallback aggregation (4-pass, h intermediate) ----
__global__ __launch_bounds__(256) void k_agg(
    const unsigned short* __restrict__ xrs, const int* __restrict__ S,
    const int* __restrict__ cnt, const int* __restrict__ psrc,
    float* __restrict__ h, const float* __restrict__ b1,
    const float* __restrict__ w2rel, const float* __restrict__ w2root,
    float* __restrict__ y, int r0, int pass) {
  int n = blockIdx.x * 4 + (threadIdx.x >> 6);
  int lane = threadIdx.x & 63;
  if (n >= N_NODES) return;
  f32x4 acc;
  if (pass == 0) acc = (f32x4){0.f, 0.f, 0.f, 0.f};
  else acc = *(const f32x4*)(h + (size_t)n * D_HID + lane * 4);

  int nr = (pass < 3) ? 2 : 1;
  for (int rr = 0; rr < nr; rr++) {
    int bin = (r0 + rr) * N_NODES + n;
    int c = cnt[bin];
    if (c > 0) {
      int p = S[bin];
      f32x4 s = (f32x4){0.f, 0.f, 0.f, 0.f};
      int e = 0;
      for (; e + 1 < c; e += 2) {
        int s0 = psrc[p + e], s1 = psrc[p + e + 1];
        ushort4 g0 = *(const ushort4*)(xrs + ((size_t)rr * N_NODES + s0) * D_HID + lane * 4);
        ushort4 g1 = *(const ushort4*)(xrs + ((size_t)rr * N_NODES + s1) * D_HID + lane * 4);
        s += bf4(g0) + bf4(g1);
      }
      if (e < c) {
        int s0 = psrc[p + e];
        ushort4 g0 = *(const ushort4*)(xrs + ((size_t)rr * N_NODES + s0) * D_HID + lane * 4);
        s += bf4(g0);
      }
      acc += s * (1.0f / (float)c);
    }
  }

  if (pass < 3) {
    *(f32x4*)(h + (size_t)n * D_HID + lane * 4) = acc;
    return;
  }

  ushort4 gr = *(const ushort4*)(xrs + ((size_t)1 * N_NODES + n) * D_HID + lane * 4);
  acc += bf4(gr);
  f32x4 b = *(const f32x4*)(b1 + lane * 4);
  f32x4 hv;
  hv[0] = fmaxf(acc[0] + b[0], 0.f);
  hv[1] = fmaxf(acc[1] + b[1], 0.f);
  hv[2] = fmaxf(acc[2] + b[2], 0.f);
  hv[3] = fmaxf(acc[3] + b[3], 0.f);

#pragma unroll
  for (int m = 0; m < 8; m++) {
    const float* wp = (m < N_REL) ? (w2rel + m * (D_HID * 2)) : w2root;
    f32x4 wa = *(const f32x4*)(wp + lane * 8);
    f32x4 wb = *(const f32x4*)(wp + lane * 8 + 4);
    float d0 = hv[0] * wa[0] + hv[1] * wa[2] + hv[2] * wb[0] + hv[3] * wb[2];
    float d1 = hv[0] * wa[1] + hv[1] * wa[3] + hv[2] * wb[1] + hv[3] * wb[3];
#pragma unroll
    for (int off = 32; off > 0; off >>= 1) {
      d0 += __shfl_down(d0, off);
      d1 += __shfl_down(d1, off);
    }
    if (lane == 0) {
      y[(size_t)m * (N_NODES * 2) + n * 2]     = d0;
      y[(size_t)m * (N_NODES * 2) + n * 2 + 1] = d1;
    }
  }
}

// ---- layer-2 aggregation: thread per bin (mean over bin) + root/bias threads ----
__global__ void k_out(const float* __restrict__ y, const float* __restrict__ b2,
                      const int* __restrict__ cnt, const int* __restrict__ S,
                      const int* __restrict__ psrc, float* __restrict__ out) {
  int t = blockIdx.x * blockDim.x + threadIdx.x;
  if (t < NBINS) {
    int c = cnt[t];
    if (c == 0) return;
    int p = S[t];
    int r = t / N_NODES;
    int i = t - r * N_NODES;
    const float* yr = y + (size_t)r * (N_NODES * 2);
    float s0 = 0.f, s1 = 0.f;
    for (int e = 0; e < c; e++) {
      int sc = psrc[p + e];
      float2 v = *(const float2*)(yr + sc * 2);
      s0 += v.x; s1 += v.y;
    }
    float is = 1.0f / (float)c;
    atomicAdd(out + (size_t)i * 2,     s0 * is);
    atomicAdd(out + (size_t)i * 2 + 1, s1 * is);
  } else if (t < NBINS + N_NODES) {
    int i = t - NBINS;
    float2 v = *(const float2*)(y + (size_t)N_REL * (N_NODES * 2) + i * 2);
    atomicAdd(out + (size_t)i * 2,     v.x + b2[0]);
    atomicAdd(out + (size_t)i * 2 + 1, v.y + b2[1]);
  }
}

// ---- fallback workspace layout; total 199,611,968 w/ xb ----
#define OFF_WT   0u            // 8*26*8192*2 = 3,407,872
#define OFF_XRS  3407872u      // 2 slabs     = 51,200,000
#define OFF_H    54607872u     // 51,200,000
#define OFF_CNT  105807872u    // 1,400,000
#define OFF_RANK 107207872u    // 1,400,000
#define OFF_S    108607872u    // 1,400,000
#define OFF_PSRC 110007872u    // 3,200,000
#define OFF_Y    113207872u    // 3,200,000
#define OFF_BSUM 116407872u    // 2048
#define OFF_BOFF 116409920u    // 2048
#define OFF_XB   116411968u    // 26*50000*32*2 = 83,200,000
#define WS_NEED_XB 199611968ull

// ---- FULL layout: 8-slab xrs, no h; total 302,011,968 ----
#define F_OFF_WT   0u            // 3,407,872
#define F_OFF_XRS  3407872u      // 8*50000*256*2 = 204,800,000
#define F_OFF_CNT  208207872u    // 1,400,000
#define F_OFF_RANK 209607872u    // 1,400,000
#define F_OFF_S    211007872u    // 1,400,000
#define F_OFF_PSRC 212407872u    // 3,200,000
#define F_OFF_Y    215607872u    // 3,200,000
#define F_OFF_BSUM 218807872u    // 2048
#define F_OFF_BOFF 218809920u    // 2048
#define F_OFF_XB   218811968u    // 83,200,000
#define WS_NEED_FULL 302011968ull

extern "C" void kernel_launch(void* const* d_in, const int* in_sizes, int n_in,
                              void* d_out, int out_size, void* d_ws, size_t ws_size,
                              hipStream_t stream) {
  const float* x      = (const float*)d_in[0];
  const int*   eidx   = (const int*)d_in[1];
  const int*   etype  = (const int*)d_in[2];
  const float* w1rel  = (const float*)d_in[3];
  const float* w1root = (const float*)d_in[4];
  const float* b1     = (const float*)d_in[5];
  const float* w2rel  = (const float*)d_in[6];
  const float* w2root = (const float*)d_in[7];
  const float* b2     = (const float*)d_in[8];
  float* out = (float*)d_out;
  char* ws = (char*)d_ws;
  const int* esrc = eidx;
  const int* edst = eidx + N_EDGES;

  const bool full = (ws_size >= WS_NEED_FULL);
  const bool big  = !full && (ws_size >= WS_NEED_XB);

  hipMemsetAsync(d_out, 0, (size_t)out_size * sizeof(float), stream);

  if (full) {
    unsigned short* wt  = (unsigned short*)(ws + F_OFF_WT);
    unsigned short* xrs = (unsigned short*)(ws + F_OFF_XRS);
    int*   cnt  = (int*)(ws + F_OFF_CNT);
    int*   rank = (int*)(ws + F_OFF_RANK);
    int*   S    = (int*)(ws + F_OFF_S);
    int*   psrc = (int*)(ws + F_OFF_PSRC);
    float* y    = (float*)(ws + F_OFF_Y);
    int*   bsum = (int*)(ws + F_OFF_BSUM);
    int*   boff = (int*)(ws + F_OFF_BOFF);
    unsigned short* xb = (unsigned short*)(ws + F_OFF_XB);

    hipMemsetAsync(ws + F_OFF_CNT, 0, 2800000u, stream);       // cnt + rank

    k_conv_w<<<8 * NCHUNK, 256, 0, stream>>>(w1rel, w1root, wt);
    k_xbf<<<(NCHUNK * N_NODES * 4 + 255) / 256, 256, 0, stream>>>(x, xb);
    k_count<<<(N_EDGES + 255) / 256, 256, 0, stream>>>(etype, edst, cnt);
    k_scan1<<<NSCANB, 256, 0, stream>>>(cnt, bsum);
    k_scan2<<<1, 512, 0, stream>>>(bsum, boff);
    k_scan3<<<NSCANB, 256, 0, stream>>>(cnt, boff, S);
    k_scatter<<<(N_EDGES + 255) / 256, 256, 0, stream>>>(etype, edst, esrc, S, rank, psrc);

    k_gemm_g<1, 8><<<NXTILE * 8, 512, 0, stream>>>(xb, wt, xrs, 0);
    k_agg8<<<(N_NODES + 3) / 4, 256, 0, stream>>>(xrs, S, cnt, psrc,
                                                  b1, w2rel, w2root, y);
    k_out<<<(NBINS + N_NODES + 255) / 256, 256, 0, stream>>>(y, b2, cnt, S, psrc, out);
    return;
  }

  unsigned short* wt  = (unsigned short*)(ws + OFF_WT);
  unsigned short* xrs = (unsigned short*)(ws + OFF_XRS);
  float* h    = (float*)(ws + OFF_H);
  int*   cnt  = (int*)(ws + OFF_CNT);
  int*   rank = (int*)(ws + OFF_RANK);
  int*   S    = (int*)(ws + OFF_S);
  int*   psrc = (int*)(ws + OFF_PSRC);
  float* y    = (float*)(ws + OFF_Y);
  int*   bsum = (int*)(ws + OFF_BSUM);
  int*   boff = (int*)(ws + OFF_BOFF);
  unsigned short* xb = (unsigned short*)(ws + OFF_XB);

  hipMemsetAsync(ws + OFF_CNT, 0, 2800000u, stream);           // cnt + rank

  k_conv_w<<<8 * NCHUNK, 256, 0, stream>>>(w1rel, w1root, wt);
  if (big)
    k_xbf<<<(NCHUNK * N_NODES * 4 + 255) / 256, 256, 0, stream>>>(x, xb);
  k_count<<<(N_EDGES + 255) / 256, 256, 0, stream>>>(etype, edst, cnt);
  k_scan1<<<NSCANB, 256, 0, stream>>>(cnt, bsum);
  k_scan2<<<1, 512, 0, stream>>>(bsum, boff);
  k_scan3<<<NSCANB, 256, 0, stream>>>(cnt, boff, S);
  k_scatter<<<(N_EDGES + 255) / 256, 256, 0, stream>>>(etype, edst, esrc, S, rank, psrc);

  for (int p = 0; p < 4; p++) {
    if (big)
      k_gemm_g<0, 2><<<dim3(NXTILE, 2), 512, 0, stream>>>(xb, wt, xrs, 2 * p);
    else
      k_gemm_f<<<dim3(782, 2), 256, 0, stream>>>(x, wt, xrs, 2 * p);
    k_agg<<<(N_NODES + 3) / 4, 256, 0, stream>>>(xrs, S, cnt, psrc, h,
                                                 b1, w2rel, w2root, y, 2 * p, p);
  }

  k_out<<<(NBINS + N_NODES + 255) / 256, 256, 0, stream>>>(y, b2, cnt, S, psrc, out);
}